// Round 1
// baseline (3594.661 us; speedup 1.0000x reference)
//
#include <hip/hip_runtime.h>

typedef __attribute__((ext_vector_type(8))) short bfrag8;   // 8 x bf16 (4 VGPRs)
typedef __attribute__((ext_vector_type(4))) float facc4;    // 4 x f32 accum

#define DEV_INLINE __device__ __forceinline__

DEV_INLINE short f2bf(float f) {
    union { float f; unsigned u; } x; x.f = f;
    unsigned r = (x.u + 0x7FFFu + ((x.u >> 16) & 1u)) >> 16;
    return (short)r;
}

// ---------------- embedding gather: h[s][2048] = embed[ids[s]][:] ----------------
__global__ __launch_bounds__(256) void embed_kernel(const int* __restrict__ ids,
                                                    const float* __restrict__ emb,
                                                    float* __restrict__ h) {
    int s = blockIdx.x;
    int id = ids[s];
    const float* src = emb + (size_t)id * 2048;
    float* dst = h + (size_t)s * 2048;
    int t = threadIdx.x;
    float4 a = *(const float4*)(src + t * 8);
    float4 b = *(const float4*)(src + t * 8 + 4);
    *(float4*)(dst + t * 8) = a;
    *(float4*)(dst + t * 8 + 4) = b;
}

// ---------------- RMSNorm over rows of 2048 ----------------
__global__ __launch_bounds__(256) void rmsnorm_kernel(const float* __restrict__ in,
                                                      const float* __restrict__ w,
                                                      float* __restrict__ out) {
    int row = blockIdx.x;
    const float* x = in + (size_t)row * 2048;
    float* y = out + (size_t)row * 2048;
    int t = threadIdx.x;
    float4 a = *(const float4*)(x + t * 8);
    float4 b = *(const float4*)(x + t * 8 + 4);
    float ss = a.x*a.x + a.y*a.y + a.z*a.z + a.w*a.w
             + b.x*b.x + b.y*b.y + b.z*b.z + b.w*b.w;
#pragma unroll
    for (int off = 32; off >= 1; off >>= 1) ss += __shfl_xor(ss, off);
    __shared__ float red[4];
    if ((t & 63) == 0) red[t >> 6] = ss;
    __syncthreads();
    float tot = red[0] + red[1] + red[2] + red[3];
    float sc = rsqrtf(tot * (1.0f / 2048.0f) + 1e-6f);
    float4 wa = *(const float4*)(w + t * 8);
    float4 wb = *(const float4*)(w + t * 8 + 4);
    float4 oa, ob;
    oa.x = a.x * sc * wa.x; oa.y = a.y * sc * wa.y;
    oa.z = a.z * sc * wa.z; oa.w = a.w * sc * wa.w;
    ob.x = b.x * sc * wb.x; ob.y = b.y * sc * wb.y;
    ob.z = b.z * sc * wb.z; ob.w = b.w * sc * wb.w;
    *(float4*)(y + t * 8) = oa;
    *(float4*)(y + t * 8 + 4) = ob;
}

// ---------------- GEMM: C[M][N] = A[M][K] * B[K][N], f32 in/out, bf16 MFMA ----------------
// Tile 128x128, BK=32, 4 waves (each 64x64 quadrant via 4x4 of 16x16x32 MFMA).
__global__ __launch_bounds__(256) void gemm_kernel(const float* __restrict__ A,
                                                   const float* __restrict__ B,
                                                   float* __restrict__ C,
                                                   int K, int N) {
    __shared__ short As[128][32];   // [row][k], 64B rows
    __shared__ short Bs[128][40];   // [col][k] transposed, 80B stride (pad kills conflicts)
    int tid = threadIdx.x;
    int lane = tid & 63, wave = tid >> 6;
    int bm = blockIdx.x * 128, bn = blockIdx.y * 128;
    int wr = (wave >> 1) * 64, wc = (wave & 1) * 64;
    int lr = lane & 15, lg = lane >> 4;

    facc4 acc[4][4];
#pragma unroll
    for (int m = 0; m < 4; ++m)
#pragma unroll
        for (int n = 0; n < 4; ++n) acc[m][n] = (facc4){0.f, 0.f, 0.f, 0.f};

    int arow = tid >> 3;          // 0..31
    int akc  = (tid & 7) * 4;     // k-offset for A stage
    int bcol = tid & 127;         // col for B stage
    int bkr  = (tid >> 7) * 16;   // k-range start for B stage

    for (int k0 = 0; k0 < K; k0 += 32) {
        // stage A tile (f32 -> bf16)
#pragma unroll
        for (int p = 0; p < 4; ++p) {
            int row = arow + p * 32;
            const float* src = A + (size_t)(bm + row) * K + k0 + akc;
            float4 v = *(const float4*)src;
            short* d = &As[row][akc];
            d[0] = f2bf(v.x); d[1] = f2bf(v.y); d[2] = f2bf(v.z); d[3] = f2bf(v.w);
        }
        // stage B tile transposed: column-walk in global (coalesced across threads)
        {
            const float* src = B + (size_t)(k0 + bkr) * N + bn + bcol;
            short tmp[16];
#pragma unroll
            for (int i = 0; i < 16; ++i) tmp[i] = f2bf(src[(size_t)i * N]);
            short* d = &Bs[bcol][bkr];
#pragma unroll
            for (int i = 0; i < 16; ++i) d[i] = tmp[i];
        }
        __syncthreads();
        bfrag8 a[4], b[4];
#pragma unroll
        for (int m = 0; m < 4; ++m)
            a[m] = *(const bfrag8*)&As[wr + m * 16 + lr][lg * 8];
#pragma unroll
        for (int n = 0; n < 4; ++n)
            b[n] = *(const bfrag8*)&Bs[wc + n * 16 + lr][lg * 8];
#pragma unroll
        for (int m = 0; m < 4; ++m)
#pragma unroll
            for (int n = 0; n < 4; ++n)
                acc[m][n] = __builtin_amdgcn_mfma_f32_16x16x32_bf16(a[m], b[n], acc[m][n], 0, 0, 0);
        __syncthreads();
    }
#pragma unroll
    for (int m = 0; m < 4; ++m)
#pragma unroll
        for (int n = 0; n < 4; ++n)
#pragma unroll
            for (int r = 0; r < 4; ++r) {
                int row = bm + wr + m * 16 + lg * 4 + r;
                int col = bn + wc + n * 16 + lr;
                C[(size_t)row * N + col] = acc[m][n][r];
            }
}

// ---------------- RoPE preps ----------------
// inv_freq(j) = 10000^(-j/64) = exp2(-j * log2(10000)/64)
#define ROPE_C 0.20762050593046010f

// Q: qnew[s][h*128+d] (f32, post-GEMM) -> Qb[h][s][d] bf16 with rope(pos=2048+s)
__global__ __launch_bounds__(128) void prep_q_kernel(const float* __restrict__ qnew,
                                                     short* __restrict__ Qb) {
    int h = blockIdx.x, s = blockIdx.y, d = threadIdx.x;
    const float* src = qnew + (size_t)s * 2048 + h * 128;
    float x = src[d], xp = src[d ^ 64];
    int j = d & 63;
    float f = (float)(2048 + s) * exp2f(-(float)j * ROPE_C);
    float c = cosf(f), sn = sinf(f);
    float o = (d < 64) ? (x * c - xp * sn) : (x * c + xp * sn);
    Qb[((size_t)h * 2048 + s) * 128 + d] = f2bf(o);
}

// K: cache[h][t][d] (t<2048) + knew[s][(h/2)*128+d] (t=2048+s) -> Kf[h][t][d] bf16, rope(pos=t)
__global__ __launch_bounds__(128) void prep_k_kernel(const float* __restrict__ kc,
                                                     const float* __restrict__ knew,
                                                     short* __restrict__ Kf) {
    int h = blockIdx.x, t = blockIdx.y, d = threadIdx.x;
    float x, xp;
    if (t < 2048) {
        const float* src = kc + ((size_t)h * 2048 + t) * 128;
        x = src[d]; xp = src[d ^ 64];
    } else {
        const float* src = knew + (size_t)(t - 2048) * 1024 + (h >> 1) * 128;
        x = src[d]; xp = src[d ^ 64];
    }
    int j = d & 63;
    float f = (float)t * exp2f(-(float)j * ROPE_C);
    float c = cosf(f), sn = sinf(f);
    float o = (d < 64) ? (x * c - xp * sn) : (x * c + xp * sn);
    Kf[((size_t)h * 4096 + t) * 128 + d] = f2bf(o);
}

// V: cache + vnew -> Vt[h][d][t] bf16 (transposed via LDS, coalesced both sides)
__global__ __launch_bounds__(256) void prep_v_kernel(const float* __restrict__ vc,
                                                     const float* __restrict__ vnew,
                                                     short* __restrict__ Vt) {
    int h = blockIdx.x;
    int t0 = blockIdx.y * 64;
    __shared__ short Lt[128][72];   // [d][t-local], 144B stride
    int tid = threadIdx.x;
    int r = tid >> 2;               // 0..63 (t-local)
    int c0 = (tid & 3) * 32;        // d-chunk
    int t = t0 + r;
    const float* src = (t < 2048)
        ? vc + ((size_t)h * 2048 + t) * 128 + c0
        : vnew + (size_t)(t - 2048) * 1024 + (h >> 1) * 128 + c0;
#pragma unroll
    for (int i = 0; i < 32; i += 4) {
        float4 v = *(const float4*)(src + i);
        Lt[c0 + i + 0][r] = f2bf(v.x);
        Lt[c0 + i + 1][r] = f2bf(v.y);
        Lt[c0 + i + 2][r] = f2bf(v.z);
        Lt[c0 + i + 3][r] = f2bf(v.w);
    }
    __syncthreads();
    int d = tid >> 1;
    int hh = (tid & 1) * 32;
    short* dst = Vt + ((size_t)h * 128 + d) * 4096 + t0 + hh;
    const short* srcl = &Lt[d][hh];
#pragma unroll
    for (int i = 0; i < 32; i += 8)
        *(bfrag8*)(dst + i) = *(const bfrag8*)(srcl + i);
}

// ---------------- flash attention ----------------
// Q[16][2048][128] bf16, Kf[16][4096][128] bf16, Vt[16][128][4096] bf16 -> O[s][h*128+d] f32
// block = (head, 64 q-rows); 4 waves x 16 q-rows each; key tiles of 32.
__global__ __launch_bounds__(256) void attn_kernel(const short* __restrict__ Q,
                                                   const short* __restrict__ Kf,
                                                   const short* __restrict__ Vt,
                                                   float* __restrict__ O) {
    int h = blockIdx.x;
    int qb = blockIdx.y * 64;
    int tid = threadIdx.x;
    int lane = tid & 63, wave = tid >> 6;
    int lr = lane & 15, lg = lane >> 4;
    int qrow = qb + wave * 16;

    __shared__ short P[4][16][40];  // per-wave private P bounce (C-layout -> A-layout)

    bfrag8 aq[4];
    {
        const short* qp = Q + ((size_t)h * 2048 + qrow + lr) * 128 + lg * 8;
#pragma unroll
        for (int dt = 0; dt < 4; ++dt) aq[dt] = *(const bfrag8*)(qp + dt * 32);
    }
    facc4 o[8];
#pragma unroll
    for (int n = 0; n < 8; ++n) o[n] = (facc4){0.f, 0.f, 0.f, 0.f};
    float mrow[4] = {-1e30f, -1e30f, -1e30f, -1e30f};
    float lrow[4] = {0.f, 0.f, 0.f, 0.f};
    int qg[4];
#pragma unroll
    for (int r = 0; r < 4; ++r) qg[r] = 2048 + qrow + lg * 4 + r;

    int numk = 2048 + qb + 64;      // multiple of 32; covers all visible keys for this block
    const float sc = 0.08838834764831845f;  // 1/sqrt(128)

    for (int t0 = 0; t0 < numk; t0 += 32) {
        facc4 s[2];
#pragma unroll
        for (int sub = 0; sub < 2; ++sub) {
            s[sub] = (facc4){0.f, 0.f, 0.f, 0.f};
            const short* kp = Kf + ((size_t)h * 4096 + t0 + sub * 16 + lr) * 128 + lg * 8;
#pragma unroll
            for (int dt = 0; dt < 4; ++dt) {
                bfrag8 bk = *(const bfrag8*)(kp + dt * 32);
                s[sub] = __builtin_amdgcn_mfma_f32_16x16x32_bf16(aq[dt], bk, s[sub], 0, 0, 0);
            }
        }
        float tm[4];
#pragma unroll
        for (int r = 0; r < 4; ++r) {
#pragma unroll
            for (int sub = 0; sub < 2; ++sub) {
                int key = t0 + sub * 16 + lr;
                float v = s[sub][r] * sc;
                if (key > qg[r]) v = -1e30f;
                s[sub][r] = v;
            }
            tm[r] = fmaxf(s[0][r], s[1][r]);
        }
#pragma unroll
        for (int off = 1; off < 16; off <<= 1)
#pragma unroll
            for (int r = 0; r < 4; ++r) tm[r] = fmaxf(tm[r], __shfl_xor(tm[r], off));
        float alpha[4], psum[4];
#pragma unroll
        for (int r = 0; r < 4; ++r) {
            float mn = fmaxf(mrow[r], tm[r]);
            alpha[r] = __expf(mrow[r] - mn);
            mrow[r] = mn;
            float p0 = __expf(s[0][r] - mn);
            float p1 = __expf(s[1][r] - mn);
            s[0][r] = p0; s[1][r] = p1;
            psum[r] = p0 + p1;
        }
#pragma unroll
        for (int off = 1; off < 16; off <<= 1)
#pragma unroll
            for (int r = 0; r < 4; ++r) psum[r] += __shfl_xor(psum[r], off);
#pragma unroll
        for (int r = 0; r < 4; ++r) lrow[r] = lrow[r] * alpha[r] + psum[r];
#pragma unroll
        for (int n = 0; n < 8; ++n)
#pragma unroll
            for (int r = 0; r < 4; ++r) o[n][r] *= alpha[r];
        // P (C-layout) -> LDS -> A-layout fragment; per-wave private, DS in-order
#pragma unroll
        for (int r = 0; r < 4; ++r) {
            P[wave][lg * 4 + r][lr]      = f2bf(s[0][r]);
            P[wave][lg * 4 + r][16 + lr] = f2bf(s[1][r]);
        }
        bfrag8 ap = *(const bfrag8*)&P[wave][lr][lg * 8];
#pragma unroll
        for (int n = 0; n < 8; ++n) {
            const short* vp = Vt + ((size_t)h * 128 + n * 16 + lr) * 4096 + t0 + lg * 8;
            bfrag8 bv = *(const bfrag8*)vp;
            o[n] = __builtin_amdgcn_mfma_f32_16x16x32_bf16(ap, bv, o[n], 0, 0, 0);
        }
    }
#pragma unroll
    for (int n = 0; n < 8; ++n)
#pragma unroll
        for (int r = 0; r < 4; ++r) {
            int row = qrow + lg * 4 + r;
            int col = h * 128 + n * 16 + lr;
            O[(size_t)row * 2048 + col] = o[n][r] / lrow[r];
        }
}

// ---------------- elementwise ----------------
__global__ __launch_bounds__(256) void add_kernel(float* __restrict__ a, const float* __restrict__ b) {
    size_t i = ((size_t)blockIdx.x * 256 + threadIdx.x) * 4;
    float4 x = *(const float4*)(a + i);
    float4 y = *(const float4*)(b + i);
    x.x += y.x; x.y += y.y; x.z += y.z; x.w += y.w;
    *(float4*)(a + i) = x;
}

__global__ __launch_bounds__(256) void silu_mul_kernel(float* __restrict__ g, const float* __restrict__ u) {
    size_t i = ((size_t)blockIdx.x * 256 + threadIdx.x) * 4;
    float4 x = *(const float4*)(g + i);
    float4 y = *(const float4*)(u + i);
    x.x = x.x / (1.f + __expf(-x.x)) * y.x;
    x.y = x.y / (1.f + __expf(-x.y)) * y.y;
    x.z = x.z / (1.f + __expf(-x.z)) * y.z;
    x.w = x.w / (1.f + __expf(-x.w)) * y.w;
    *(float4*)(g + i) = x;
}

// ---------------- orchestration ----------------
extern "C" void kernel_launch(void* const* d_in, const int* in_sizes, int n_in,
                              void* d_out, int out_size, void* d_ws, size_t ws_size,
                              hipStream_t stream) {
    const int*   ids   = (const int*)d_in[0];
    const float* emb   = (const float*)d_in[1];
    const float* Wq    = (const float*)d_in[2];
    const float* Wk    = (const float*)d_in[3];
    const float* Wv    = (const float*)d_in[4];
    const float* Wo    = (const float*)d_in[5];
    const float* Wg    = (const float*)d_in[6];
    const float* Wu    = (const float*)d_in[7];
    const float* Wd    = (const float*)d_in[8];
    const float* ln1   = (const float*)d_in[9];
    const float* ln2   = (const float*)d_in[10];
    const float* fnorm = (const float*)d_in[11];
    const float* lmh   = (const float*)d_in[12];
    const float* kc    = (const float*)d_in[13];
    const float* vc    = (const float*)d_in[14];
    float* logits = (float*)d_out;

    char* ws = (char*)d_ws;
    float* hbuf = (float*)(ws + ((size_t)0 << 20));    // 16 MB
    float* xbuf = (float*)(ws + ((size_t)16 << 20));   // 16 MB
    float* qbuf = (float*)(ws + ((size_t)32 << 20));   // 16 MB
    float* kbuf = (float*)(ws + ((size_t)48 << 20));   // 8 MB
    float* vbuf = (float*)(ws + ((size_t)56 << 20));   // 8 MB
    float* obuf = (float*)(ws + ((size_t)64 << 20));   // 16 MB
    float* gbuf = (float*)(ws + ((size_t)80 << 20));   // 64 MB
    float* ubuf = (float*)(ws + ((size_t)144 << 20));  // 64 MB
    short* Qb   = (short*)(ws + ((size_t)208 << 20));  // 8 MB bf16
    short* Kf   = (short*)(ws + ((size_t)216 << 20));  // 16 MB bf16
    short* Vt   = (short*)(ws + ((size_t)232 << 20));  // 16 MB bf16  (total 248 MB)

    embed_kernel<<<2048, 256, 0, stream>>>(ids, emb, hbuf);

    for (int l = 0; l < 2; ++l) {
        const float* wq  = Wq + (size_t)l * 2048 * 2048;
        const float* wk  = Wk + (size_t)l * 2048 * 1024;
        const float* wv  = Wv + (size_t)l * 2048 * 1024;
        const float* wo  = Wo + (size_t)l * 2048 * 2048;
        const float* wg  = Wg + (size_t)l * 2048 * 8192;
        const float* wu  = Wu + (size_t)l * 2048 * 8192;
        const float* wd  = Wd + (size_t)l * 8192 * 2048;
        const float* l1  = ln1 + (size_t)l * 2048;
        const float* l2  = ln2 + (size_t)l * 2048;
        const float* kcl = kc + (size_t)l * 16 * 2048 * 128;
        const float* vcl = vc + (size_t)l * 16 * 2048 * 128;

        rmsnorm_kernel<<<2048, 256, 0, stream>>>(hbuf, l1, xbuf);
        gemm_kernel<<<dim3(16, 16), 256, 0, stream>>>(xbuf, wq, qbuf, 2048, 2048);
        gemm_kernel<<<dim3(16, 8),  256, 0, stream>>>(xbuf, wk, kbuf, 2048, 1024);
        gemm_kernel<<<dim3(16, 8),  256, 0, stream>>>(xbuf, wv, vbuf, 2048, 1024);
        prep_q_kernel<<<dim3(16, 2048), 128, 0, stream>>>(qbuf, Qb);
        prep_k_kernel<<<dim3(16, 4096), 128, 0, stream>>>(kcl, kbuf, Kf);
        prep_v_kernel<<<dim3(16, 64), 256, 0, stream>>>(vcl, vbuf, Vt);
        attn_kernel<<<dim3(16, 32), 256, 0, stream>>>(Qb, Kf, Vt, obuf);
        gemm_kernel<<<dim3(16, 16), 256, 0, stream>>>(obuf, wo, qbuf, 2048, 2048);
        add_kernel<<<4096, 256, 0, stream>>>(hbuf, qbuf);
        rmsnorm_kernel<<<2048, 256, 0, stream>>>(hbuf, l2, xbuf);
        gemm_kernel<<<dim3(16, 64), 256, 0, stream>>>(xbuf, wg, gbuf, 2048, 8192);
        gemm_kernel<<<dim3(16, 64), 256, 0, stream>>>(xbuf, wu, ubuf, 2048, 8192);
        silu_mul_kernel<<<16384, 256, 0, stream>>>(gbuf, ubuf);
        gemm_kernel<<<dim3(16, 16), 256, 0, stream>>>(gbuf, wd, qbuf, 8192, 2048);
        add_kernel<<<4096, 256, 0, stream>>>(hbuf, qbuf);
    }
    rmsnorm_kernel<<<2048, 256, 0, stream>>>(hbuf, fnorm, xbuf);
    gemm_kernel<<<dim3(16, 250), 256, 0, stream>>>(xbuf, lmh, logits, 2048, 32000);
}

// Round 2
// 2668.078 us; speedup vs baseline: 1.3473x; 1.3473x over previous
//
#include <hip/hip_runtime.h>

typedef __attribute__((ext_vector_type(8))) short bfrag8;   // 8 x bf16 (4 VGPRs)
typedef __attribute__((ext_vector_type(4))) short bfrag4;   // 4 x bf16
typedef __attribute__((ext_vector_type(4))) float facc4;    // 4 x f32 accum

#define DEV_INLINE __device__ __forceinline__

DEV_INLINE short f2bf(float f) {
    union { float f; unsigned u; } x; x.f = f;
    unsigned r = (x.u + 0x7FFFu + ((x.u >> 16) & 1u)) >> 16;
    return (short)r;
}

// async global->LDS, 16B per lane; dest must be linear in lane order
#define GL2LDS(gp, lp) __builtin_amdgcn_global_load_lds( \
    (const __attribute__((address_space(1))) void*)(gp), \
    (__attribute__((address_space(3))) void*)(lp), 16, 0, 0)

// ---------------- embedding gather ----------------
__global__ __launch_bounds__(256) void embed_kernel(const int* __restrict__ ids,
                                                    const float* __restrict__ emb,
                                                    float* __restrict__ h) {
    int s = blockIdx.x;
    int id = ids[s];
    const float* src = emb + (size_t)id * 2048;
    float* dst = h + (size_t)s * 2048;
    int t = threadIdx.x;
    float4 a = *(const float4*)(src + t * 8);
    float4 b = *(const float4*)(src + t * 8 + 4);
    *(float4*)(dst + t * 8) = a;
    *(float4*)(dst + t * 8 + 4) = b;
}

// ---------------- RMSNorm rows of 2048, bf16 out ----------------
__global__ __launch_bounds__(256) void rmsnorm_bf16_kernel(const float* __restrict__ in,
                                                           const float* __restrict__ w,
                                                           short* __restrict__ out) {
    int row = blockIdx.x;
    const float* x = in + (size_t)row * 2048;
    short* y = out + (size_t)row * 2048;
    int t = threadIdx.x;
    float4 a = *(const float4*)(x + t * 8);
    float4 b = *(const float4*)(x + t * 8 + 4);
    float ss = a.x*a.x + a.y*a.y + a.z*a.z + a.w*a.w
             + b.x*b.x + b.y*b.y + b.z*b.z + b.w*b.w;
#pragma unroll
    for (int off = 32; off >= 1; off >>= 1) ss += __shfl_xor(ss, off);
    __shared__ float red[4];
    if ((t & 63) == 0) red[t >> 6] = ss;
    __syncthreads();
    float tot = red[0] + red[1] + red[2] + red[3];
    float sc = rsqrtf(tot * (1.0f / 2048.0f) + 1e-6f);
    float4 wa = *(const float4*)(w + t * 8);
    float4 wb = *(const float4*)(w + t * 8 + 4);
    bfrag8 o;
    o[0] = f2bf(a.x * sc * wa.x); o[1] = f2bf(a.y * sc * wa.y);
    o[2] = f2bf(a.z * sc * wa.z); o[3] = f2bf(a.w * sc * wa.w);
    o[4] = f2bf(b.x * sc * wb.x); o[5] = f2bf(b.y * sc * wb.y);
    o[6] = f2bf(b.z * sc * wb.z); o[7] = f2bf(b.w * sc * wb.w);
    *(bfrag8*)(y + t * 8) = o;
}

// ---------------- weight transpose-convert: W[K][N] f32 -> Wt[N][K] bf16 ----------------
__global__ __launch_bounds__(256) void wconv_kernel(const float* __restrict__ W,
                                                    short* __restrict__ Wt,
                                                    int K, int N) {
    __shared__ short Lt[64][72];           // [n][k], 144B stride (16B-aligned rows)
    int k0 = blockIdx.x * 64, n0 = blockIdx.y * 64;
    int tid = threadIdx.x;
    int r = tid >> 4, c = (tid & 15) * 4;  // r 0..15, c 0..60
#pragma unroll
    for (int j = 0; j < 4; ++j) {
        int k = r + j * 16;
        float4 v = *(const float4*)(W + (size_t)(k0 + k) * N + n0 + c);
        Lt[c + 0][k] = f2bf(v.x); Lt[c + 1][k] = f2bf(v.y);
        Lt[c + 2][k] = f2bf(v.z); Lt[c + 3][k] = f2bf(v.w);
    }
    __syncthreads();
    int n = tid >> 3, kk = (tid & 7) * 8;  // n 0..31, kk 0..56
#pragma unroll
    for (int j = 0; j < 2; ++j)
        *(bfrag8*)(Wt + (size_t)(n0 + n + j * 32) * K + k0 + kk) = *(const bfrag8*)&Lt[n + j * 32][kk];
}

// ---------------- GEMM: C[M][N] = A[M][K] * Bt[N][K]^T, bf16 in, f32 out ----------------
// m97 structure: BMx128 tile, BK=32, global_load_lds(16B) staging, 2 barriers/K-step.
template<int BM>
__global__ __launch_bounds__(256) void gemm_bt(const short* __restrict__ A,
                                               const short* __restrict__ Bt,
                                               float* __restrict__ C,
                                               int K, int N) {
    __shared__ short As[BM * 32];
    __shared__ short Bs[128 * 32];
    constexpr int NW = (BM == 128) ? 4 : 2;
    int tid = threadIdx.x;
    int lane = tid & 63, wave = tid >> 6;
    int bm = blockIdx.x * BM, bn = blockIdx.y * 128;
    int wr = (BM == 128) ? ((wave >> 1) * 64) : 0;
    int wc = (BM == 128) ? ((wave & 1) * 64) : (wave * 32);
    int lr = lane & 15, lg = lane >> 4;

    facc4 acc[4][NW];
#pragma unroll
    for (int m = 0; m < 4; ++m)
#pragma unroll
        for (int n = 0; n < NW; ++n) acc[m][n] = (facc4){0.f, 0.f, 0.f, 0.f};

    int stR = wave * 16 + (lane >> 2);     // staging row (lane-linear: 16B/lane)
    int stK = (lane & 3) * 8;
    const short* Ag = A + (size_t)(bm + stR) * K + stK;
    const short* Bg = Bt + (size_t)(bn + stR) * K + stK;
    short* AsP = As + stR * 32 + stK;
    short* BsP = Bs + stR * 32 + stK;

    for (int k0 = 0; k0 < K; k0 += 32) {
        GL2LDS(Ag + k0, AsP);
        if (BM == 128) GL2LDS(Ag + (size_t)64 * K + k0, AsP + 64 * 32);
        GL2LDS(Bg + k0, BsP);
        GL2LDS(Bg + (size_t)64 * K + k0, BsP + 64 * 32);
        __syncthreads();
        bfrag8 a[4], b[NW];
#pragma unroll
        for (int m = 0; m < 4; ++m)
            a[m] = *(const bfrag8*)&As[(wr + m * 16 + lr) * 32 + lg * 8];
#pragma unroll
        for (int n = 0; n < NW; ++n)
            b[n] = *(const bfrag8*)&Bs[(wc + n * 16 + lr) * 32 + lg * 8];
#pragma unroll
        for (int m = 0; m < 4; ++m)
#pragma unroll
            for (int n = 0; n < NW; ++n)
                acc[m][n] = __builtin_amdgcn_mfma_f32_16x16x32_bf16(a[m], b[n], acc[m][n], 0, 0, 0);
        __syncthreads();
    }
#pragma unroll
    for (int m = 0; m < 4; ++m)
#pragma unroll
        for (int n = 0; n < NW; ++n)
#pragma unroll
            for (int r = 0; r < 4; ++r)
                C[(size_t)(bm + wr + m * 16 + lg * 4 + r) * N + bn + wc + n * 16 + lr] = acc[m][n][r];
}

// ---------------- RoPE ----------------
#define ROPE_C 0.20762050593046010f   // log2(10000)/64
#define INV2PI 0.15915494309189535f
#define TWOPI  6.283185307179586f

DEV_INLINE void rope_sc(float pos, int j, float* s, float* c) {
    float f = pos * exp2f(-(float)j * ROPE_C);
    float r = f * INV2PI;
    r -= floorf(r);                   // [0,1): safe small arg for fast sincos
    __sincosf(r * TWOPI, s, c);
}

// Q: qkv[s][h*128+d] -> Qb[h][s][d] bf16, rope(pos=2048+s)
__global__ __launch_bounds__(128) void prep_q_kernel(const float* __restrict__ qkv,
                                                     short* __restrict__ Qb) {
    int h = blockIdx.x, s = blockIdx.y, d = threadIdx.x;
    const float* src = qkv + (size_t)s * 4096 + h * 128;
    float x = src[d], xp = src[d ^ 64];
    float sn, c;
    rope_sc((float)(2048 + s), d & 63, &sn, &c);
    float o = (d < 64) ? (x * c - xp * sn) : (x * c + xp * sn);
    Qb[((size_t)h * 2048 + s) * 128 + d] = f2bf(o);
}

// K: cache[h][t][d] (t<2048) + qkv[s][2048+(h/2)*128+d] -> Kf[h][t][d] bf16, rope(pos=t)
__global__ __launch_bounds__(128) void prep_k_kernel(const float* __restrict__ kc,
                                                     const float* __restrict__ qkv,
                                                     short* __restrict__ Kf) {
    int h = blockIdx.x, t = blockIdx.y, d = threadIdx.x;
    float x, xp;
    if (t < 2048) {
        const float* src = kc + ((size_t)h * 2048 + t) * 128;
        x = src[d]; xp = src[d ^ 64];
    } else {
        const float* src = qkv + (size_t)(t - 2048) * 4096 + 2048 + (h >> 1) * 128;
        x = src[d]; xp = src[d ^ 64];
    }
    float sn, c;
    rope_sc((float)t, d & 63, &sn, &c);
    float o = (d < 64) ? (x * c - xp * sn) : (x * c + xp * sn);
    Kf[((size_t)h * 4096 + t) * 128 + d] = f2bf(o);
}

// V: cache + qkv(col 3072+) -> Vt[h][d][t] bf16 (transposed)
__global__ __launch_bounds__(256) void prep_v_kernel(const float* __restrict__ vc,
                                                     const float* __restrict__ qkv,
                                                     short* __restrict__ Vt) {
    int h = blockIdx.x;
    int t0 = blockIdx.y * 64;
    __shared__ short Lt[128][72];
    int tid = threadIdx.x;
    int r = tid >> 2;
    int c0 = (tid & 3) * 32;
    int t = t0 + r;
    const float* src = (t < 2048)
        ? vc + ((size_t)h * 2048 + t) * 128 + c0
        : qkv + (size_t)(t - 2048) * 4096 + 3072 + (h >> 1) * 128 + c0;
#pragma unroll
    for (int i = 0; i < 32; i += 4) {
        float4 v = *(const float4*)(src + i);
        Lt[c0 + i + 0][r] = f2bf(v.x);
        Lt[c0 + i + 1][r] = f2bf(v.y);
        Lt[c0 + i + 2][r] = f2bf(v.z);
        Lt[c0 + i + 3][r] = f2bf(v.w);
    }
    __syncthreads();
    int d = tid >> 1;
    int hh = (tid & 1) * 32;
    short* dst = Vt + ((size_t)h * 128 + d) * 4096 + t0 + hh;
    const short* srcl = &Lt[d][hh];
#pragma unroll
    for (int i = 0; i < 32; i += 8)
        *(bfrag8*)(dst + i) = *(const bfrag8*)(srcl + i);
}

// ---------------- flash attention (bf16 out) ----------------
__global__ __launch_bounds__(256) void attn_kernel(const short* __restrict__ Q,
                                                   const short* __restrict__ Kf,
                                                   const short* __restrict__ Vt,
                                                   short* __restrict__ Ob) {
    int h = blockIdx.x;
    int qb = blockIdx.y * 64;
    int tid = threadIdx.x;
    int lane = tid & 63, wave = tid >> 6;
    int lr = lane & 15, lg = lane >> 4;
    int qrow = qb + wave * 16;

    __shared__ short P[4][16][40];

    bfrag8 aq[4];
    {
        const short* qp = Q + ((size_t)h * 2048 + qrow + lr) * 128 + lg * 8;
#pragma unroll
        for (int dt = 0; dt < 4; ++dt) aq[dt] = *(const bfrag8*)(qp + dt * 32);
    }
    facc4 o[8];
#pragma unroll
    for (int n = 0; n < 8; ++n) o[n] = (facc4){0.f, 0.f, 0.f, 0.f};
    float mrow[4] = {-1e30f, -1e30f, -1e30f, -1e30f};
    float lrow[4] = {0.f, 0.f, 0.f, 0.f};
    int qg[4];
#pragma unroll
    for (int r = 0; r < 4; ++r) qg[r] = 2048 + qrow + lg * 4 + r;

    int numk = 2048 + qb + 64;
    const float sc = 0.08838834764831845f;

    for (int t0 = 0; t0 < numk; t0 += 32) {
        facc4 s[2];
#pragma unroll
        for (int sub = 0; sub < 2; ++sub) {
            s[sub] = (facc4){0.f, 0.f, 0.f, 0.f};
            const short* kp = Kf + ((size_t)h * 4096 + t0 + sub * 16 + lr) * 128 + lg * 8;
#pragma unroll
            for (int dt = 0; dt < 4; ++dt) {
                bfrag8 bk = *(const bfrag8*)(kp + dt * 32);
                s[sub] = __builtin_amdgcn_mfma_f32_16x16x32_bf16(aq[dt], bk, s[sub], 0, 0, 0);
            }
        }
        float tm[4];
#pragma unroll
        for (int r = 0; r < 4; ++r) {
#pragma unroll
            for (int sub = 0; sub < 2; ++sub) {
                int key = t0 + sub * 16 + lr;
                float v = s[sub][r] * sc;
                if (key > qg[r]) v = -1e30f;
                s[sub][r] = v;
            }
            tm[r] = fmaxf(s[0][r], s[1][r]);
        }
#pragma unroll
        for (int off = 1; off < 16; off <<= 1)
#pragma unroll
            for (int r = 0; r < 4; ++r) tm[r] = fmaxf(tm[r], __shfl_xor(tm[r], off));
        float alpha[4], psum[4];
#pragma unroll
        for (int r = 0; r < 4; ++r) {
            float mn = fmaxf(mrow[r], tm[r]);
            alpha[r] = __expf(mrow[r] - mn);
            mrow[r] = mn;
            float p0 = __expf(s[0][r] - mn);
            float p1 = __expf(s[1][r] - mn);
            s[0][r] = p0; s[1][r] = p1;
            psum[r] = p0 + p1;
        }
#pragma unroll
        for (int off = 1; off < 16; off <<= 1)
#pragma unroll
            for (int r = 0; r < 4; ++r) psum[r] += __shfl_xor(psum[r], off);
#pragma unroll
        for (int r = 0; r < 4; ++r) lrow[r] = lrow[r] * alpha[r] + psum[r];
#pragma unroll
        for (int n = 0; n < 8; ++n)
#pragma unroll
            for (int r = 0; r < 4; ++r) o[n][r] *= alpha[r];
#pragma unroll
        for (int r = 0; r < 4; ++r) {
            P[wave][lg * 4 + r][lr]      = f2bf(s[0][r]);
            P[wave][lg * 4 + r][16 + lr] = f2bf(s[1][r]);
        }
        bfrag8 ap = *(const bfrag8*)&P[wave][lr][lg * 8];
#pragma unroll
        for (int n = 0; n < 8; ++n) {
            const short* vp = Vt + ((size_t)h * 128 + n * 16 + lr) * 4096 + t0 + lg * 8;
            bfrag8 bv = *(const bfrag8*)vp;
            o[n] = __builtin_amdgcn_mfma_f32_16x16x32_bf16(ap, bv, o[n], 0, 0, 0);
        }
    }
#pragma unroll
    for (int n = 0; n < 8; ++n)
#pragma unroll
        for (int r = 0; r < 4; ++r)
            Ob[(size_t)(qrow + lg * 4 + r) * 2048 + h * 128 + n * 16 + lr] = f2bf(o[n][r] / lrow[r]);
}

// ---------------- elementwise ----------------
__global__ __launch_bounds__(256) void add_kernel(float* __restrict__ a, const float* __restrict__ b) {
    size_t i = ((size_t)blockIdx.x * 256 + threadIdx.x) * 4;
    float4 x = *(const float4*)(a + i);
    float4 y = *(const float4*)(b + i);
    x.x += y.x; x.y += y.y; x.z += y.z; x.w += y.w;
    *(float4*)(a + i) = x;
}

__global__ __launch_bounds__(256) void silu_mul_bf16_kernel(const float* __restrict__ g,
                                                            const float* __restrict__ u,
                                                            short* __restrict__ out) {
    size_t i = ((size_t)blockIdx.x * 256 + threadIdx.x) * 4;
    float4 x = *(const float4*)(g + i);
    float4 y = *(const float4*)(u + i);
    bfrag4 o;
    o[0] = f2bf(x.x / (1.f + __expf(-x.x)) * y.x);
    o[1] = f2bf(x.y / (1.f + __expf(-x.y)) * y.y);
    o[2] = f2bf(x.z / (1.f + __expf(-x.z)) * y.z);
    o[3] = f2bf(x.w / (1.f + __expf(-x.w)) * y.w);
    *(bfrag4*)(out + i) = o;
}

// ---------------- orchestration ----------------
extern "C" void kernel_launch(void* const* d_in, const int* in_sizes, int n_in,
                              void* d_out, int out_size, void* d_ws, size_t ws_size,
                              hipStream_t stream) {
    const int*   ids   = (const int*)d_in[0];
    const float* emb   = (const float*)d_in[1];
    const float* Wq    = (const float*)d_in[2];
    const float* Wk    = (const float*)d_in[3];
    const float* Wv    = (const float*)d_in[4];
    const float* Wo    = (const float*)d_in[5];
    const float* Wg    = (const float*)d_in[6];
    const float* Wu    = (const float*)d_in[7];
    const float* Wd    = (const float*)d_in[8];
    const float* ln1   = (const float*)d_in[9];
    const float* ln2   = (const float*)d_in[10];
    const float* fnorm = (const float*)d_in[11];
    const float* lmh   = (const float*)d_in[12];
    const float* kc    = (const float*)d_in[13];
    const float* vc    = (const float*)d_in[14];
    float* logits = (float*)d_out;

    char* ws = (char*)d_ws;
    float* hbuf   = (float*)(ws + ((size_t)0 << 20));    // 16 MB f32 residual
    short* xb     = (short*)(ws + ((size_t)16 << 20));   // 8 MB bf16 normed x
    float* qkvbuf = (float*)(ws + ((size_t)24 << 20));   // 32 MB f32 [2048][4096] (also GEMM-C scratch)
    short* Ob     = (short*)(ws + ((size_t)56 << 20));   // 8 MB bf16 attn out
    short* wt     = (short*)(ws + ((size_t)64 << 20));   // 34 MB bf16 transposed weight scratch
    short* Qb     = (short*)(ws + ((size_t)98 << 20));   // 8 MB
    short* Kf     = (short*)(ws + ((size_t)106 << 20));  // 16 MB
    short* Vt     = (short*)(ws + ((size_t)122 << 20));  // 16 MB
    float* gbuf   = (float*)(ws + ((size_t)138 << 20));  // 64 MB
    float* ubuf   = (float*)(ws + ((size_t)202 << 20));  // 64 MB
    short* gb     = (short*)(ws + ((size_t)266 << 20));  // 32 MB  (high water 298 MB)
    short* lmwt   = (short*)(ws + ((size_t)138 << 20));  // 131 MB, reuses gbuf/ubuf/gb region

    embed_kernel<<<2048, 256, 0, stream>>>(ids, emb, hbuf);

    for (int l = 0; l < 2; ++l) {
        const float* wq  = Wq + (size_t)l * 2048 * 2048;
        const float* wk  = Wk + (size_t)l * 2048 * 1024;
        const float* wv  = Wv + (size_t)l * 2048 * 1024;
        const float* wo  = Wo + (size_t)l * 2048 * 2048;
        const float* wg  = Wg + (size_t)l * 2048 * 8192;
        const float* wu  = Wu + (size_t)l * 2048 * 8192;
        const float* wd  = Wd + (size_t)l * 8192 * 2048;
        const float* l1  = ln1 + (size_t)l * 2048;
        const float* l2  = ln2 + (size_t)l * 2048;
        const float* kcl = kc + (size_t)l * 16 * 2048 * 128;
        const float* vcl = vc + (size_t)l * 16 * 2048 * 128;

        rmsnorm_bf16_kernel<<<2048, 256, 0, stream>>>(hbuf, l1, xb);
        // fused QKV: Wt rows [0,2048)=q, [2048,3072)=k, [3072,4096)=v
        wconv_kernel<<<dim3(32, 32), 256, 0, stream>>>(wq, wt, 2048, 2048);
        wconv_kernel<<<dim3(32, 16), 256, 0, stream>>>(wk, wt + (size_t)2048 * 2048, 2048, 1024);
        wconv_kernel<<<dim3(32, 16), 256, 0, stream>>>(wv, wt + (size_t)3072 * 2048, 2048, 1024);
        gemm_bt<128><<<dim3(16, 32), 256, 0, stream>>>(xb, wt, qkvbuf, 2048, 4096);
        prep_q_kernel<<<dim3(16, 2048), 128, 0, stream>>>(qkvbuf, Qb);
        prep_k_kernel<<<dim3(16, 4096), 128, 0, stream>>>(kcl, qkvbuf, Kf);
        prep_v_kernel<<<dim3(16, 64), 256, 0, stream>>>(vcl, qkvbuf, Vt);
        attn_kernel<<<dim3(16, 32), 256, 0, stream>>>(Qb, Kf, Vt, Ob);
        wconv_kernel<<<dim3(32, 32), 256, 0, stream>>>(wo, wt, 2048, 2048);
        gemm_bt<64><<<dim3(32, 16), 256, 0, stream>>>(Ob, wt, qkvbuf, 2048, 2048);
        add_kernel<<<4096, 256, 0, stream>>>(hbuf, qkvbuf);
        rmsnorm_bf16_kernel<<<2048, 256, 0, stream>>>(hbuf, l2, xb);
        wconv_kernel<<<dim3(32, 128), 256, 0, stream>>>(wg, wt, 2048, 8192);
        gemm_bt<128><<<dim3(16, 64), 256, 0, stream>>>(xb, wt, gbuf, 2048, 8192);
        wconv_kernel<<<dim3(32, 128), 256, 0, stream>>>(wu, wt, 2048, 8192);
        gemm_bt<128><<<dim3(16, 64), 256, 0, stream>>>(xb, wt, ubuf, 2048, 8192);
        silu_mul_bf16_kernel<<<16384, 256, 0, stream>>>(gbuf, ubuf, gb);
        wconv_kernel<<<dim3(128, 32), 256, 0, stream>>>(wd, wt, 8192, 2048);
        gemm_bt<64><<<dim3(32, 16), 256, 0, stream>>>(gb, wt, qkvbuf, 8192, 2048);
        add_kernel<<<4096, 256, 0, stream>>>(hbuf, qkvbuf);
    }
    rmsnorm_bf16_kernel<<<2048, 256, 0, stream>>>(hbuf, fnorm, xb);
    wconv_kernel<<<dim3(32, 500), 256, 0, stream>>>(lmh, lmwt, 2048, 32000);
    gemm_bt<128><<<dim3(16, 250), 256, 0, stream>>>(xb, lmwt, logits, 2048, 32000);
}

// Round 3
// 2600.697 us; speedup vs baseline: 1.3822x; 1.0259x over previous
//
#include <hip/hip_runtime.h>

typedef __attribute__((ext_vector_type(8))) short bfrag8;   // 8 x bf16 (4 VGPRs)
typedef __attribute__((ext_vector_type(4))) short bfrag4;   // 4 x bf16
typedef __attribute__((ext_vector_type(4))) float facc4;    // 4 x f32 accum

#define DEV_INLINE __device__ __forceinline__

DEV_INLINE short f2bf(float f) {
    union { float f; unsigned u; } x; x.f = f;
    unsigned r = (x.u + 0x7FFFu + ((x.u >> 16) & 1u)) >> 16;
    return (short)r;
}

DEV_INLINE unsigned pack_bf2(float a, float b) {
    return (unsigned)(unsigned short)f2bf(a) | ((unsigned)(unsigned short)f2bf(b) << 16);
}

// async global->LDS, 16B per lane; dest must be linear in lane order
#define GL2LDS(gp, lp) __builtin_amdgcn_global_load_lds( \
    (const __attribute__((address_space(1))) void*)(gp), \
    (__attribute__((address_space(3))) void*)(lp), 16, 0, 0)

// ---------------- embedding gather ----------------
__global__ __launch_bounds__(256) void embed_kernel(const int* __restrict__ ids,
                                                    const float* __restrict__ emb,
                                                    float* __restrict__ h) {
    int s = blockIdx.x;
    int id = ids[s];
    const float* src = emb + (size_t)id * 2048;
    float* dst = h + (size_t)s * 2048;
    int t = threadIdx.x;
    float4 a = *(const float4*)(src + t * 8);
    float4 b = *(const float4*)(src + t * 8 + 4);
    *(float4*)(dst + t * 8) = a;
    *(float4*)(dst + t * 8 + 4) = b;
}

// ---------------- RMSNorm rows of 2048, bf16 out ----------------
__global__ __launch_bounds__(256) void rmsnorm_bf16_kernel(const float* __restrict__ in,
                                                           const float* __restrict__ w,
                                                           short* __restrict__ out) {
    int row = blockIdx.x;
    const float* x = in + (size_t)row * 2048;
    short* y = out + (size_t)row * 2048;
    int t = threadIdx.x;
    float4 a = *(const float4*)(x + t * 8);
    float4 b = *(const float4*)(x + t * 8 + 4);
    float ss = a.x*a.x + a.y*a.y + a.z*a.z + a.w*a.w
             + b.x*b.x + b.y*b.y + b.z*b.z + b.w*b.w;
#pragma unroll
    for (int off = 32; off >= 1; off >>= 1) ss += __shfl_xor(ss, off);
    __shared__ float red[4];
    if ((t & 63) == 0) red[t >> 6] = ss;
    __syncthreads();
    float tot = red[0] + red[1] + red[2] + red[3];
    float sc = rsqrtf(tot * (1.0f / 2048.0f) + 1e-6f);
    float4 wa = *(const float4*)(w + t * 8);
    float4 wb = *(const float4*)(w + t * 8 + 4);
    bfrag8 o;
    o[0] = f2bf(a.x * sc * wa.x); o[1] = f2bf(a.y * sc * wa.y);
    o[2] = f2bf(a.z * sc * wa.z); o[3] = f2bf(a.w * sc * wa.w);
    o[4] = f2bf(b.x * sc * wb.x); o[5] = f2bf(b.y * sc * wb.y);
    o[6] = f2bf(b.z * sc * wb.z); o[7] = f2bf(b.w * sc * wb.w);
    *(bfrag8*)(y + t * 8) = o;
}

// ---------------- weight transpose-convert: W[K][N] f32 -> Wt[N][K] bf16 ----------------
__global__ __launch_bounds__(256) void wconv_kernel(const float* __restrict__ W,
                                                    short* __restrict__ Wt,
                                                    int K, int N) {
    __shared__ short Lt[64][72];           // [n][k], 144B stride (16B-aligned rows)
    int k0 = blockIdx.x * 64, n0 = blockIdx.y * 64;
    int tid = threadIdx.x;
    int r = tid >> 4, c = (tid & 15) * 4;  // r 0..15, c 0..60
#pragma unroll
    for (int j = 0; j < 4; ++j) {
        int k = r + j * 16;
        float4 v = *(const float4*)(W + (size_t)(k0 + k) * N + n0 + c);
        Lt[c + 0][k] = f2bf(v.x); Lt[c + 1][k] = f2bf(v.y);
        Lt[c + 2][k] = f2bf(v.z); Lt[c + 3][k] = f2bf(v.w);
    }
    __syncthreads();
    int n = tid >> 3, kk = (tid & 7) * 8;  // n 0..31, kk 0..56
#pragma unroll
    for (int j = 0; j < 2; ++j)
        *(bfrag8*)(Wt + (size_t)(n0 + n + j * 32) * K + k0 + kk) = *(const bfrag8*)&Lt[n + j * 32][kk];
}

// ---------------- GEMM: C[M][N] = A[M][K] * Bt[N][K]^T, bf16 in, f32 out ----------------
template<int BM>
__global__ __launch_bounds__(256) void gemm_bt(const short* __restrict__ A,
                                               const short* __restrict__ Bt,
                                               float* __restrict__ C,
                                               int K, int N) {
    __shared__ short As[BM * 32];
    __shared__ short Bs[128 * 32];
    constexpr int NW = (BM == 128) ? 4 : 2;
    int tid = threadIdx.x;
    int lane = tid & 63, wave = tid >> 6;
    int bm = blockIdx.x * BM, bn = blockIdx.y * 128;
    int wr = (BM == 128) ? ((wave >> 1) * 64) : 0;
    int wc = (BM == 128) ? ((wave & 1) * 64) : (wave * 32);
    int lr = lane & 15, lg = lane >> 4;

    facc4 acc[4][NW];
#pragma unroll
    for (int m = 0; m < 4; ++m)
#pragma unroll
        for (int n = 0; n < NW; ++n) acc[m][n] = (facc4){0.f, 0.f, 0.f, 0.f};

    int stR = wave * 16 + (lane >> 2);     // staging row (lane-linear: 16B/lane)
    int stK = (lane & 3) * 8;
    const short* Ag = A + (size_t)(bm + stR) * K + stK;
    const short* Bg = Bt + (size_t)(bn + stR) * K + stK;
    short* AsP = As + stR * 32 + stK;
    short* BsP = Bs + stR * 32 + stK;

    for (int k0 = 0; k0 < K; k0 += 32) {
        GL2LDS(Ag + k0, AsP);
        if (BM == 128) GL2LDS(Ag + (size_t)64 * K + k0, AsP + 64 * 32);
        GL2LDS(Bg + k0, BsP);
        GL2LDS(Bg + (size_t)64 * K + k0, BsP + 64 * 32);
        __syncthreads();
        bfrag8 a[4], b[NW];
#pragma unroll
        for (int m = 0; m < 4; ++m)
            a[m] = *(const bfrag8*)&As[(wr + m * 16 + lr) * 32 + lg * 8];
#pragma unroll
        for (int n = 0; n < NW; ++n)
            b[n] = *(const bfrag8*)&Bs[(wc + n * 16 + lr) * 32 + lg * 8];
#pragma unroll
        for (int m = 0; m < 4; ++m)
#pragma unroll
            for (int n = 0; n < NW; ++n)
                acc[m][n] = __builtin_amdgcn_mfma_f32_16x16x32_bf16(a[m], b[n], acc[m][n], 0, 0, 0);
        __syncthreads();
    }
#pragma unroll
    for (int m = 0; m < 4; ++m)
#pragma unroll
        for (int n = 0; n < NW; ++n)
#pragma unroll
            for (int r = 0; r < 4; ++r)
                C[(size_t)(bm + wr + m * 16 + lg * 4 + r) * N + bn + wc + n * 16 + lr] = acc[m][n][r];
}

// ---------------- RoPE ----------------
#define ROPE_C 0.20762050593046010f   // log2(10000)/64
#define INV2PI 0.15915494309189535f
#define TWOPI  6.283185307179586f
#define QK_SCALE 0.08838834764831845f // 1/sqrt(128), folded into Q

DEV_INLINE void rope_sc(float pos, int j, float* s, float* c) {
    float f = pos * exp2f(-(float)j * ROPE_C);
    float r = f * INV2PI;
    r -= floorf(r);
    __sincosf(r * TWOPI, s, c);
}

// Q: qkv[s][h*128+d] -> Qb[h][s][d] bf16, rope(pos=2048+s), pre-scaled by 1/sqrt(D)
__global__ __launch_bounds__(128) void prep_q_kernel(const float* __restrict__ qkv,
                                                     short* __restrict__ Qb) {
    int h = blockIdx.x, s = blockIdx.y, d = threadIdx.x;
    const float* src = qkv + (size_t)s * 4096 + h * 128;
    float x = src[d], xp = src[d ^ 64];
    float sn, c;
    rope_sc((float)(2048 + s), d & 63, &sn, &c);
    float o = (d < 64) ? (x * c - xp * sn) : (x * c + xp * sn);
    Qb[((size_t)h * 2048 + s) * 128 + d] = f2bf(o * QK_SCALE);
}

// K: cache[h][t][d] (t<2048) + qkv[s][2048+(h/2)*128+d] -> Kf[h][t][d] bf16, rope(pos=t)
__global__ __launch_bounds__(128) void prep_k_kernel(const float* __restrict__ kc,
                                                     const float* __restrict__ qkv,
                                                     short* __restrict__ Kf) {
    int h = blockIdx.x, t = blockIdx.y, d = threadIdx.x;
    float x, xp;
    if (t < 2048) {
        const float* src = kc + ((size_t)h * 2048 + t) * 128;
        x = src[d]; xp = src[d ^ 64];
    } else {
        const float* src = qkv + (size_t)(t - 2048) * 4096 + 2048 + (h >> 1) * 128;
        x = src[d]; xp = src[d ^ 64];
    }
    float sn, c;
    rope_sc((float)t, d & 63, &sn, &c);
    float o = (d < 64) ? (x * c - xp * sn) : (x * c + xp * sn);
    Kf[((size_t)h * 4096 + t) * 128 + d] = f2bf(o);
}

// V: cache + qkv(col 3072+) -> Vt[h][d][t] bf16 (transposed)
__global__ __launch_bounds__(256) void prep_v_kernel(const float* __restrict__ vc,
                                                     const float* __restrict__ qkv,
                                                     short* __restrict__ Vt) {
    int h = blockIdx.x;
    int t0 = blockIdx.y * 64;
    __shared__ short Lt[128][72];
    int tid = threadIdx.x;
    int r = tid >> 2;
    int c0 = (tid & 3) * 32;
    int t = t0 + r;
    const float* src = (t < 2048)
        ? vc + ((size_t)h * 2048 + t) * 128 + c0
        : qkv + (size_t)(t - 2048) * 4096 + 3072 + (h >> 1) * 128 + c0;
#pragma unroll
    for (int i = 0; i < 32; i += 4) {
        float4 v = *(const float4*)(src + i);
        Lt[c0 + i + 0][r] = f2bf(v.x);
        Lt[c0 + i + 1][r] = f2bf(v.y);
        Lt[c0 + i + 2][r] = f2bf(v.z);
        Lt[c0 + i + 3][r] = f2bf(v.w);
    }
    __syncthreads();
    int d = tid >> 1;
    int hh = (tid & 1) * 32;
    short* dst = Vt + ((size_t)h * 128 + d) * 4096 + t0 + hh;
    const short* srcl = &Lt[d][hh];
#pragma unroll
    for (int i = 0; i < 32; i += 8)
        *(bfrag8*)(dst + i) = *(const bfrag8*)(srcl + i);
}

// ---------------- flash attention v2 ----------------
// Swapped QK^T (S^T = mfma(K,Q)): per-lane softmax state (q = lane&15).
// Register double-buffered K/V fragments prefetched one 32-key tile ahead.
__global__ __launch_bounds__(256, 2) void attn_kernel(const short* __restrict__ Q,
                                                      const short* __restrict__ Kf,
                                                      const short* __restrict__ Vt,
                                                      short* __restrict__ Ob) {
    int h = blockIdx.x;
    int qb = blockIdx.y * 64;
    int tid = threadIdx.x;
    int lane = tid & 63, wave = tid >> 6;
    int lr = lane & 15, lg = lane >> 4;
    int qrow = qb + wave * 16;
    int qg = 2048 + qrow + lr;            // this lane's global q position

    __shared__ short P[4][16][40];        // per-wave private [q][k] bounce

    const short* kbase = Kf + (size_t)h * 4096 * 128;
    const short* vbase = Vt + (size_t)h * 128 * 4096;

    bfrag8 aq[4];
    {
        const short* qp = Q + ((size_t)h * 2048 + qrow + lr) * 128 + lg * 8;
#pragma unroll
        for (int dt = 0; dt < 4; ++dt) aq[dt] = *(const bfrag8*)(qp + dt * 32);
    }
    facc4 o[8];
#pragma unroll
    for (int n = 0; n < 8; ++n) o[n] = (facc4){0.f, 0.f, 0.f, 0.f};
    float m = -1e30f, l = 0.f;

    auto loadK = [&](bfrag8* dst, int t0) {
#pragma unroll
        for (int dt = 0; dt < 4; ++dt) {
            dst[dt]     = *(const bfrag8*)(kbase + (size_t)(t0 + lr) * 128 + dt * 32 + lg * 8);
            dst[4 + dt] = *(const bfrag8*)(kbase + (size_t)(t0 + 16 + lr) * 128 + dt * 32 + lg * 8);
        }
    };
    auto loadV = [&](bfrag8* dst, int t0) {
#pragma unroll
        for (int n = 0; n < 8; ++n)
            dst[n] = *(const bfrag8*)(vbase + (size_t)(n * 16 + lr) * 4096 + t0 + lg * 8);
    };
    auto process = [&](const bfrag8* kf, const bfrag8* vf, int t0) {
        facc4 s0 = (facc4){0.f, 0.f, 0.f, 0.f}, s1 = (facc4){0.f, 0.f, 0.f, 0.f};
#pragma unroll
        for (int dt = 0; dt < 4; ++dt) {
            s0 = __builtin_amdgcn_mfma_f32_16x16x32_bf16(kf[dt],     aq[dt], s0, 0, 0, 0);
            s1 = __builtin_amdgcn_mfma_f32_16x16x32_bf16(kf[4 + dt], aq[dt], s1, 0, 0, 0);
        }
        // S^T layout: s0[r] = S[key=t0+lg*4+r][q=lr], s1: key+16
        float mx = m;
#pragma unroll
        for (int r = 0; r < 4; ++r) {
            int k0 = t0 + lg * 4 + r;
            if (k0 > qg)      s0[r] = -1e30f;
            if (k0 + 16 > qg) s1[r] = -1e30f;
            mx = fmaxf(mx, fmaxf(s0[r], s1[r]));
        }
        mx = fmaxf(mx, __shfl_xor(mx, 16));
        mx = fmaxf(mx, __shfl_xor(mx, 32));
        float alpha = __expf(m - mx);
        m = mx;
        float ps = 0.f;
#pragma unroll
        for (int r = 0; r < 4; ++r) {
            s0[r] = __expf(s0[r] - mx); ps += s0[r];
            s1[r] = __expf(s1[r] - mx); ps += s1[r];
        }
        ps += __shfl_xor(ps, 16);
        ps += __shfl_xor(ps, 32);
        l = l * alpha + ps;
        // write P[q=lr][k] (identical layout to the PV A-fragment read)
        unsigned* prow = (unsigned*)&P[wave][lr][0];
        prow[lg * 2]     = pack_bf2(s0[0], s0[1]);
        prow[lg * 2 + 1] = pack_bf2(s0[2], s0[3]);
        prow[8 + lg * 2]     = pack_bf2(s1[0], s1[1]);
        prow[8 + lg * 2 + 1] = pack_bf2(s1[2], s1[3]);
        bfrag8 ap = *(const bfrag8*)&P[wave][lr][lg * 8];
        float ab[4];
#pragma unroll
        for (int r = 0; r < 4; ++r) ab[r] = __shfl(alpha, lg * 4 + r);
#pragma unroll
        for (int n = 0; n < 8; ++n) {
            o[n][0] *= ab[0]; o[n][1] *= ab[1]; o[n][2] *= ab[2]; o[n][3] *= ab[3];
        }
#pragma unroll
        for (int n = 0; n < 8; ++n)
            o[n] = __builtin_amdgcn_mfma_f32_16x16x32_bf16(ap, vf[n], o[n], 0, 0, 0);
    };

    int ntiles = ((2048 + qrow) >> 5) + 1;
    bfrag8 kA[8], vA[8], kB[8], vB[8];
    loadK(kA, 0); loadV(vA, 0);
    int i = 0;
    for (;;) {
        if (i + 1 < ntiles) { loadK(kB, (i + 1) * 32); loadV(vB, (i + 1) * 32); }
        process(kA, vA, i * 32);
        if (++i >= ntiles) break;
        if (i + 1 < ntiles) { loadK(kA, (i + 1) * 32); loadV(vA, (i + 1) * 32); }
        process(kB, vB, i * 32);
        if (++i >= ntiles) break;
    }

    float lb[4];
#pragma unroll
    for (int r = 0; r < 4; ++r) lb[r] = 1.0f / __shfl(l, lg * 4 + r);
#pragma unroll
    for (int n = 0; n < 8; ++n)
#pragma unroll
        for (int r = 0; r < 4; ++r)
            Ob[(size_t)(qrow + lg * 4 + r) * 2048 + h * 128 + n * 16 + lr] = f2bf(o[n][r] * lb[r]);
}

// ---------------- elementwise ----------------
__global__ __launch_bounds__(256) void add_kernel(float* __restrict__ a, const float* __restrict__ b) {
    size_t i = ((size_t)blockIdx.x * 256 + threadIdx.x) * 4;
    float4 x = *(const float4*)(a + i);
    float4 y = *(const float4*)(b + i);
    x.x += y.x; x.y += y.y; x.z += y.z; x.w += y.w;
    *(float4*)(a + i) = x;
}

__global__ __launch_bounds__(256) void silu_mul_bf16_kernel(const float* __restrict__ g,
                                                            const float* __restrict__ u,
                                                            short* __restrict__ out) {
    size_t i = ((size_t)blockIdx.x * 256 + threadIdx.x) * 4;
    float4 x = *(const float4*)(g + i);
    float4 y = *(const float4*)(u + i);
    bfrag4 o;
    o[0] = f2bf(x.x / (1.f + __expf(-x.x)) * y.x);
    o[1] = f2bf(x.y / (1.f + __expf(-x.y)) * y.y);
    o[2] = f2bf(x.z / (1.f + __expf(-x.z)) * y.z);
    o[3] = f2bf(x.w / (1.f + __expf(-x.w)) * y.w);
    *(bfrag4*)(out + i) = o;
}

// ---------------- orchestration ----------------
extern "C" void kernel_launch(void* const* d_in, const int* in_sizes, int n_in,
                              void* d_out, int out_size, void* d_ws, size_t ws_size,
                              hipStream_t stream) {
    const int*   ids   = (const int*)d_in[0];
    const float* emb   = (const float*)d_in[1];
    const float* Wq    = (const float*)d_in[2];
    const float* Wk    = (const float*)d_in[3];
    const float* Wv    = (const float*)d_in[4];
    const float* Wo    = (const float*)d_in[5];
    const float* Wg    = (const float*)d_in[6];
    const float* Wu    = (const float*)d_in[7];
    const float* Wd    = (const float*)d_in[8];
    const float* ln1   = (const float*)d_in[9];
    const float* ln2   = (const float*)d_in[10];
    const float* fnorm = (const float*)d_in[11];
    const float* lmh   = (const float*)d_in[12];
    const float* kc    = (const float*)d_in[13];
    const float* vc    = (const float*)d_in[14];
    float* logits = (float*)d_out;

    char* ws = (char*)d_ws;
    float* hbuf   = (float*)(ws + ((size_t)0 << 20));    // 16 MB f32 residual
    short* xb     = (short*)(ws + ((size_t)16 << 20));   // 8 MB bf16 normed x
    float* qkvbuf = (float*)(ws + ((size_t)24 << 20));   // 32 MB f32 [2048][4096]
    short* Ob     = (short*)(ws + ((size_t)56 << 20));   // 8 MB bf16 attn out
    short* wt     = (short*)(ws + ((size_t)64 << 20));   // 34 MB bf16 transposed weight scratch
    short* Qb     = (short*)(ws + ((size_t)98 << 20));   // 8 MB
    short* Kf     = (short*)(ws + ((size_t)106 << 20));  // 16 MB
    short* Vt     = (short*)(ws + ((size_t)122 << 20));  // 16 MB
    float* gbuf   = (float*)(ws + ((size_t)138 << 20));  // 64 MB
    float* ubuf   = (float*)(ws + ((size_t)202 << 20));  // 64 MB
    short* gb     = (short*)(ws + ((size_t)266 << 20));  // 32 MB  (high water 298 MB)
    short* lmwt   = (short*)(ws + ((size_t)138 << 20));  // 131 MB, reuses gbuf/ubuf/gb region

    embed_kernel<<<2048, 256, 0, stream>>>(ids, emb, hbuf);

    for (int l = 0; l < 2; ++l) {
        const float* wq  = Wq + (size_t)l * 2048 * 2048;
        const float* wk  = Wk + (size_t)l * 2048 * 1024;
        const float* wv  = Wv + (size_t)l * 2048 * 1024;
        const float* wo  = Wo + (size_t)l * 2048 * 2048;
        const float* wg  = Wg + (size_t)l * 2048 * 8192;
        const float* wu  = Wu + (size_t)l * 2048 * 8192;
        const float* wd  = Wd + (size_t)l * 8192 * 2048;
        const float* l1  = ln1 + (size_t)l * 2048;
        const float* l2  = ln2 + (size_t)l * 2048;
        const float* kcl = kc + (size_t)l * 16 * 2048 * 128;
        const float* vcl = vc + (size_t)l * 16 * 2048 * 128;

        rmsnorm_bf16_kernel<<<2048, 256, 0, stream>>>(hbuf, l1, xb);
        // fused QKV: Wt rows [0,2048)=q, [2048,3072)=k, [3072,4096)=v
        wconv_kernel<<<dim3(32, 32), 256, 0, stream>>>(wq, wt, 2048, 2048);
        wconv_kernel<<<dim3(32, 16), 256, 0, stream>>>(wk, wt + (size_t)2048 * 2048, 2048, 1024);
        wconv_kernel<<<dim3(32, 16), 256, 0, stream>>>(wv, wt + (size_t)3072 * 2048, 2048, 1024);
        gemm_bt<128><<<dim3(16, 32), 256, 0, stream>>>(xb, wt, qkvbuf, 2048, 4096);
        prep_q_kernel<<<dim3(16, 2048), 128, 0, stream>>>(qkvbuf, Qb);
        prep_k_kernel<<<dim3(16, 4096), 128, 0, stream>>>(kcl, qkvbuf, Kf);
        prep_v_kernel<<<dim3(16, 64), 256, 0, stream>>>(vcl, qkvbuf, Vt);
        attn_kernel<<<dim3(16, 32), 256, 0, stream>>>(Qb, Kf, Vt, Ob);
        wconv_kernel<<<dim3(32, 32), 256, 0, stream>>>(wo, wt, 2048, 2048);
        gemm_bt<64><<<dim3(32, 16), 256, 0, stream>>>(Ob, wt, qkvbuf, 2048, 2048);
        add_kernel<<<4096, 256, 0, stream>>>(hbuf, qkvbuf);
        rmsnorm_bf16_kernel<<<2048, 256, 0, stream>>>(hbuf, l2, xb);
        wconv_kernel<<<dim3(32, 128), 256, 0, stream>>>(wg, wt, 2048, 8192);
        gemm_bt<128><<<dim3(16, 64), 256, 0, stream>>>(xb, wt, gbuf, 2048, 8192);
        wconv_kernel<<<dim3(32, 128), 256, 0, stream>>>(wu, wt, 2048, 8192);
        gemm_bt<128><<<dim3(16, 64), 256, 0, stream>>>(xb, wt, ubuf, 2048, 8192);
        silu_mul_bf16_kernel<<<16384, 256, 0, stream>>>(gbuf, ubuf, gb);
        wconv_kernel<<<dim3(128, 32), 256, 0, stream>>>(wd, wt, 8192, 2048);
        gemm_bt<64><<<dim3(32, 16), 256, 0, stream>>>(gb, wt, qkvbuf, 8192, 2048);
        add_kernel<<<4096, 256, 0, stream>>>(hbuf, qkvbuf);
    }
    rmsnorm_bf16_kernel<<<2048, 256, 0, stream>>>(hbuf, fnorm, xb);
    wconv_kernel<<<dim3(32, 500), 256, 0, stream>>>(lmh, lmwt, 2048, 32000);
    gemm_bt<128><<<dim3(16, 250), 256, 0, stream>>>(xb, lmwt, logits, 2048, 32000);
}

// Round 4
// 2035.096 us; speedup vs baseline: 1.7663x; 1.2779x over previous
//
#include <hip/hip_runtime.h>

typedef __attribute__((ext_vector_type(8))) short bfrag8;   // 8 x bf16 (4 VGPRs)
typedef __attribute__((ext_vector_type(4))) short bfrag4;   // 4 x bf16
typedef __attribute__((ext_vector_type(4))) float facc4;    // 4 x f32 accum

#define DEV_INLINE __device__ __forceinline__

DEV_INLINE short f2bf(float f) {
    union { float f; unsigned u; } x; x.f = f;
    unsigned r = (x.u + 0x7FFFu + ((x.u >> 16) & 1u)) >> 16;
    return (short)r;
}

DEV_INLINE unsigned pack_bf2(float a, float b) {
    return (unsigned)(unsigned short)f2bf(a) | ((unsigned)(unsigned short)f2bf(b) << 16);
}

// async global->LDS, 16B per lane; dest = wave-uniform base + lane*16
#define GL2LDS(gp, lp) __builtin_amdgcn_global_load_lds( \
    (const __attribute__((address_space(1))) void*)(gp), \
    (__attribute__((address_space(3))) void*)(lp), 16, 0, 0)

// ---------------- embedding gather ----------------
__global__ __launch_bounds__(256) void embed_kernel(const int* __restrict__ ids,
                                                    const float* __restrict__ emb,
                                                    float* __restrict__ h) {
    int s = blockIdx.x;
    int id = ids[s];
    const float* src = emb + (size_t)id * 2048;
    float* dst = h + (size_t)s * 2048;
    int t = threadIdx.x;
    float4 a = *(const float4*)(src + t * 8);
    float4 b = *(const float4*)(src + t * 8 + 4);
    *(float4*)(dst + t * 8) = a;
    *(float4*)(dst + t * 8 + 4) = b;
}

// ---------------- RMSNorm rows of 2048, bf16 out ----------------
__global__ __launch_bounds__(256) void rmsnorm_bf16_kernel(const float* __restrict__ in,
                                                           const float* __restrict__ w,
                                                           short* __restrict__ out) {
    int row = blockIdx.x;
    const float* x = in + (size_t)row * 2048;
    short* y = out + (size_t)row * 2048;
    int t = threadIdx.x;
    float4 a = *(const float4*)(x + t * 8);
    float4 b = *(const float4*)(x + t * 8 + 4);
    float ss = a.x*a.x + a.y*a.y + a.z*a.z + a.w*a.w
             + b.x*b.x + b.y*b.y + b.z*b.z + b.w*b.w;
#pragma unroll
    for (int off = 32; off >= 1; off >>= 1) ss += __shfl_xor(ss, off);
    __shared__ float red[4];
    if ((t & 63) == 0) red[t >> 6] = ss;
    __syncthreads();
    float tot = red[0] + red[1] + red[2] + red[3];
    float sc = rsqrtf(tot * (1.0f / 2048.0f) + 1e-6f);
    float4 wa = *(const float4*)(w + t * 8);
    float4 wb = *(const float4*)(w + t * 8 + 4);
    bfrag8 o;
    o[0] = f2bf(a.x * sc * wa.x); o[1] = f2bf(a.y * sc * wa.y);
    o[2] = f2bf(a.z * sc * wa.z); o[3] = f2bf(a.w * sc * wa.w);
    o[4] = f2bf(b.x * sc * wb.x); o[5] = f2bf(b.y * sc * wb.y);
    o[6] = f2bf(b.z * sc * wb.z); o[7] = f2bf(b.w * sc * wb.w);
    *(bfrag8*)(y + t * 8) = o;
}

// ---------------- weight transpose-convert: W[K][N] f32 -> Wt[N][K] bf16 ----------------
__global__ __launch_bounds__(256) void wconv_kernel(const float* __restrict__ W,
                                                    short* __restrict__ Wt,
                                                    int K, int N) {
    __shared__ short Lt[64][72];
    int k0 = blockIdx.x * 64, n0 = blockIdx.y * 64;
    int tid = threadIdx.x;
    int r = tid >> 4, c = (tid & 15) * 4;
#pragma unroll
    for (int j = 0; j < 4; ++j) {
        int k = r + j * 16;
        float4 v = *(const float4*)(W + (size_t)(k0 + k) * N + n0 + c);
        Lt[c + 0][k] = f2bf(v.x); Lt[c + 1][k] = f2bf(v.y);
        Lt[c + 2][k] = f2bf(v.z); Lt[c + 3][k] = f2bf(v.w);
    }
    __syncthreads();
    int n = tid >> 3, kk = (tid & 7) * 8;
#pragma unroll
    for (int j = 0; j < 2; ++j)
        *(bfrag8*)(Wt + (size_t)(n0 + n + j * 32) * K + k0 + kk) = *(const bfrag8*)&Lt[n + j * 32][kk];
}

// ---------------- GEMM: C[M][N] = A[M][K] * Bt[N][K]^T, bf16 in, f32 out ----------------
// m97 structure + bijective XCD-chunked swizzle; optional fused residual add.
template<int BM, bool ADD>
__global__ __launch_bounds__(256) void gemm_bt(const short* __restrict__ A,
                                               const short* __restrict__ Bt,
                                               float* __restrict__ C,
                                               int K, int N) {
    __shared__ short As[BM * 32];
    __shared__ short Bs[128 * 32];
    constexpr int NW = (BM == 128) ? 4 : 2;
    int tid = threadIdx.x;
    int lane = tid & 63, wave = tid >> 6;

    // XCD-chunked bijective swizzle (m204): same-B-panel blocks -> same XCD L2
    int gx = gridDim.x;
    int nwg = gx * gridDim.y;
    int b = blockIdx.y * gx + blockIdx.x;
    int q = nwg >> 3, r8 = nwg & 7;
    int xcd = b & 7, idx = b >> 3;
    int lb = (xcd < r8) ? (xcd * (q + 1) + idx) : (r8 * (q + 1) + (xcd - r8) * q + idx);
    int bm = (lb % gx) * BM, bn = (lb / gx) * 128;

    int wr = (BM == 128) ? ((wave >> 1) * 64) : 0;
    int wc = (BM == 128) ? ((wave & 1) * 64) : (wave * 32);
    int lr = lane & 15, lg = lane >> 4;

    facc4 acc[4][NW];
#pragma unroll
    for (int m = 0; m < 4; ++m)
#pragma unroll
        for (int n = 0; n < NW; ++n) acc[m][n] = (facc4){0.f, 0.f, 0.f, 0.f};

    int stR = wave * 16 + (lane >> 2);     // staging row (lane-linear LDS dest)
    int stK = (lane & 3) * 8;
    const short* Ag = A + (size_t)(bm + stR) * K + stK;
    const short* Bg = Bt + (size_t)(bn + stR) * K + stK;
    short* AsP = As + stR * 32 + stK;
    short* BsP = Bs + stR * 32 + stK;

    for (int k0 = 0; k0 < K; k0 += 32) {
        GL2LDS(Ag + k0, AsP);
        if (BM == 128) GL2LDS(Ag + (size_t)64 * K + k0, AsP + 64 * 32);
        GL2LDS(Bg + k0, BsP);
        GL2LDS(Bg + (size_t)64 * K + k0, BsP + 64 * 32);
        __syncthreads();
        bfrag8 a[4], bfr[NW];
#pragma unroll
        for (int m = 0; m < 4; ++m)
            a[m] = *(const bfrag8*)&As[(wr + m * 16 + lr) * 32 + lg * 8];
#pragma unroll
        for (int n = 0; n < NW; ++n)
            bfr[n] = *(const bfrag8*)&Bs[(wc + n * 16 + lr) * 32 + lg * 8];
#pragma unroll
        for (int m = 0; m < 4; ++m)
#pragma unroll
            for (int n = 0; n < NW; ++n)
                acc[m][n] = __builtin_amdgcn_mfma_f32_16x16x32_bf16(a[m], bfr[n], acc[m][n], 0, 0, 0);
        __syncthreads();
    }
#pragma unroll
    for (int m = 0; m < 4; ++m)
#pragma unroll
        for (int n = 0; n < NW; ++n)
#pragma unroll
            for (int r = 0; r < 4; ++r) {
                size_t ci = (size_t)(bm + wr + m * 16 + lg * 4 + r) * N + bn + wc + n * 16 + lr;
                C[ci] = ADD ? (C[ci] + acc[m][n][r]) : acc[m][n][r];
            }
}

// ---------------- RoPE ----------------
#define ROPE_C 0.20762050593046010f   // log2(10000)/64
#define INV2PI 0.15915494309189535f
#define TWOPI  6.283185307179586f
#define QK_SCALE 0.08838834764831845f // 1/sqrt(128), folded into Q

DEV_INLINE void rope_sc(float pos, int j, float* s, float* c) {
    float f = pos * exp2f(-(float)j * ROPE_C);
    float r = f * INV2PI;
    r -= floorf(r);
    __sincosf(r * TWOPI, s, c);
}

__global__ __launch_bounds__(128) void prep_q_kernel(const float* __restrict__ qkv,
                                                     short* __restrict__ Qb) {
    int h = blockIdx.x, s = blockIdx.y, d = threadIdx.x;
    const float* src = qkv + (size_t)s * 4096 + h * 128;
    float x = src[d], xp = src[d ^ 64];
    float sn, c;
    rope_sc((float)(2048 + s), d & 63, &sn, &c);
    float o = (d < 64) ? (x * c - xp * sn) : (x * c + xp * sn);
    Qb[((size_t)h * 2048 + s) * 128 + d] = f2bf(o * QK_SCALE);
}

__global__ __launch_bounds__(128) void prep_k_kernel(const float* __restrict__ kc,
                                                     const float* __restrict__ qkv,
                                                     short* __restrict__ Kf) {
    int h = blockIdx.x, t = blockIdx.y, d = threadIdx.x;
    float x, xp;
    if (t < 2048) {
        const float* src = kc + ((size_t)h * 2048 + t) * 128;
        x = src[d]; xp = src[d ^ 64];
    } else {
        const float* src = qkv + (size_t)(t - 2048) * 4096 + 2048 + (h >> 1) * 128;
        x = src[d]; xp = src[d ^ 64];
    }
    float sn, c;
    rope_sc((float)t, d & 63, &sn, &c);
    float o = (d < 64) ? (x * c - xp * sn) : (x * c + xp * sn);
    Kf[((size_t)h * 4096 + t) * 128 + d] = f2bf(o);
}

__global__ __launch_bounds__(256) void prep_v_kernel(const float* __restrict__ vc,
                                                     const float* __restrict__ qkv,
                                                     short* __restrict__ Vt) {
    int h = blockIdx.x;
    int t0 = blockIdx.y * 64;
    __shared__ short Lt[128][72];
    int tid = threadIdx.x;
    int r = tid >> 2;
    int c0 = (tid & 3) * 32;
    int t = t0 + r;
    const float* src = (t < 2048)
        ? vc + ((size_t)h * 2048 + t) * 128 + c0
        : qkv + (size_t)(t - 2048) * 4096 + 3072 + (h >> 1) * 128 + c0;
#pragma unroll
    for (int i = 0; i < 32; i += 4) {
        float4 v = *(const float4*)(src + i);
        Lt[c0 + i + 0][r] = f2bf(v.x);
        Lt[c0 + i + 1][r] = f2bf(v.y);
        Lt[c0 + i + 2][r] = f2bf(v.z);
        Lt[c0 + i + 3][r] = f2bf(v.w);
    }
    __syncthreads();
    int d = tid >> 1;
    int hh = (tid & 1) * 32;
    short* dst = Vt + ((size_t)h * 128 + d) * 4096 + t0 + hh;
    const short* srcl = &Lt[d][hh];
#pragma unroll
    for (int i = 0; i < 32; i += 8)
        *(bfrag8*)(dst + i) = *(const bfrag8*)(srcl + i);
}

// ---------------- flash attention v3 ----------------
// Shared LDS K/V staging (global_load_lds, double-buffered, XOR-swizzled),
// swapped QK^T per-lane softmax, defer-max, K-split x2 (grid z) + combine.
__global__ __launch_bounds__(256, 4) void attn_kernel(const short* __restrict__ Q,
                                                      const short* __restrict__ Kf,
                                                      const short* __restrict__ Vt,
                                                      float* __restrict__ Op,
                                                      float* __restrict__ Ml,
                                                      float* __restrict__ Ll) {
    int h = blockIdx.x;
    int qb = blockIdx.y * 64;
    int z = blockIdx.z;
    int tid = threadIdx.x;
    int lane = tid & 63, wave = tid >> 6;
    int lr = lane & 15, lg = lane >> 4;
    int qrow = qb + wave * 16;
    int qg = 2048 + qrow + lr;            // this lane's global q position

    __shared__ short Ks[2][4096];         // 32 keys x 128 d, rows 256B, 16B-chunk XOR swizzle (row&7)
    __shared__ short Vs[2][4096];         // 128 d x 32 t, rows 64B, chunk XOR swizzle ((row>>1)&3)
    __shared__ short P[4][16][40];        // per-wave private [q][k] bounce

    const short* kbase = Kf + (size_t)h * 4096 * 128;
    const short* vbase = Vt + (size_t)h * 128 * 4096;

    bfrag8 aq[4];
    {
        const short* qp = Q + ((size_t)h * 2048 + qrow + lr) * 128 + lg * 8;
#pragma unroll
        for (int dt = 0; dt < 4; ++dt) aq[dt] = *(const bfrag8*)(qp + dt * 32);
    }
    facc4 o[8];
#pragma unroll
    for (int n = 0; n < 8; ++n) o[n] = (facc4){0.f, 0.f, 0.f, 0.f};
    float m = -1e30f, l = 0.f;

    // pre-swizzled-source staging (LDS dest linear: base + lane*16)
    auto stage = [&](int buf, int t0) {
#pragma unroll
        for (int half = 0; half < 2; ++half) {
            int rk = half * 16 + wave * 4 + (lane >> 4);
            int ck = (lane & 15) ^ (rk & 7);
            GL2LDS(kbase + (size_t)(t0 + rk) * 128 + ck * 8,
                   &Ks[buf][half * 2048 + wave * 512 + lane * 8]);
            int rv = half * 64 + wave * 16 + (lane >> 2);
            int cv = (lane & 3) ^ ((rv >> 1) & 3);
            GL2LDS(vbase + (size_t)rv * 4096 + t0 + cv * 8,
                   &Vs[buf][half * 2048 + wave * 512 + lane * 8]);
        }
    };

    auto process = [&](int buf, int t0) {
        facc4 s0 = (facc4){0.f, 0.f, 0.f, 0.f}, s1 = (facc4){0.f, 0.f, 0.f, 0.f};
        int r0 = lr, r1 = 16 + lr;
#pragma unroll
        for (int dt = 0; dt < 4; ++dt) {
            bfrag8 k0 = *(const bfrag8*)&Ks[buf][r0 * 128 + (((dt * 4 + lg) ^ (r0 & 7)) * 8)];
            bfrag8 k1 = *(const bfrag8*)&Ks[buf][r1 * 128 + (((dt * 4 + lg) ^ (r1 & 7)) * 8)];
            s0 = __builtin_amdgcn_mfma_f32_16x16x32_bf16(k0, aq[dt], s0, 0, 0, 0);
            s1 = __builtin_amdgcn_mfma_f32_16x16x32_bf16(k1, aq[dt], s1, 0, 0, 0);
        }
        // S^T: s0[r] = S[key=t0+lg*4+r][q=lr], s1: key+16 (scale folded into Q)
        float mx = m;
#pragma unroll
        for (int r = 0; r < 4; ++r) {
            int k0i = t0 + lg * 4 + r;
            if (k0i > qg)      s0[r] = -1e30f;
            if (k0i + 16 > qg) s1[r] = -1e30f;
            mx = fmaxf(mx, fmaxf(s0[r], s1[r]));
        }
        mx = fmaxf(mx, __shfl_xor(mx, 16));
        mx = fmaxf(mx, __shfl_xor(mx, 32));
        if (__any(mx > m + 8.f)) {        // rare: rescale o and fold max
            float alpha = __expf(m - mx); // per-lane (q = lr)
            m = mx;
            l *= alpha;
            float ab[4];
#pragma unroll
            for (int r = 0; r < 4; ++r) ab[r] = __shfl(alpha, lg * 4 + r);
#pragma unroll
            for (int n = 0; n < 8; ++n) {
                o[n][0] *= ab[0]; o[n][1] *= ab[1]; o[n][2] *= ab[2]; o[n][3] *= ab[3];
            }
        }
        float ps = 0.f;
#pragma unroll
        for (int r = 0; r < 4; ++r) {
            s0[r] = __expf(s0[r] - m); ps += s0[r];
            s1[r] = __expf(s1[r] - m); ps += s1[r];
        }
        ps += __shfl_xor(ps, 16);
        ps += __shfl_xor(ps, 32);
        l += ps;
        unsigned* prow = (unsigned*)&P[wave][lr][0];
        prow[lg * 2]     = pack_bf2(s0[0], s0[1]);
        prow[lg * 2 + 1] = pack_bf2(s0[2], s0[3]);
        prow[8 + lg * 2]     = pack_bf2(s1[0], s1[1]);
        prow[8 + lg * 2 + 1] = pack_bf2(s1[2], s1[3]);
        bfrag8 ap = *(const bfrag8*)&P[wave][lr][lg * 8];
#pragma unroll
        for (int n = 0; n < 8; ++n) {
            int rv = n * 16 + lr;
            bfrag8 vf = *(const bfrag8*)&Vs[buf][rv * 32 + ((lg ^ ((rv >> 1) & 3)) * 8)];
            o[n] = __builtin_amdgcn_mfma_f32_16x16x32_bf16(ap, vf, o[n], 0, 0, 0);
        }
    };

    int NT = ((2048 + qb + 63) >> 5) + 1; // block-uniform tile count
    int i0 = z ? (NT >> 1) : 0;
    int i1 = z ? NT : (NT >> 1);

    stage(0, i0 * 32);
    __syncthreads();
    int buf = 0;
    for (int i = i0; i < i1; ++i) {
        if (i + 1 < i1) stage(buf ^ 1, (i + 1) * 32);
        process(buf, i * 32);
        __syncthreads();
        buf ^= 1;
    }

#pragma unroll
    for (int n = 0; n < 8; ++n)
#pragma unroll
        for (int r = 0; r < 4; ++r)
            Op[(size_t)(z * 2048 + qrow + lg * 4 + r) * 2048 + h * 128 + n * 16 + lr] = o[n][r];
    if (lg == 0) {
        Ml[((size_t)z * 16 + h) * 2048 + qrow + lr] = m;
        Ll[((size_t)z * 16 + h) * 2048 + qrow + lr] = l;
    }
}

// combine the two K-split partials -> bf16 attn output
__global__ __launch_bounds__(256) void attn_combine(const float* __restrict__ Op,
                                                    const float* __restrict__ Ml,
                                                    const float* __restrict__ Ll,
                                                    short* __restrict__ Ob) {
    int row = blockIdx.x, t = threadIdx.x;
    int col0 = t * 8;
    int h = col0 >> 7;
    float m0 = Ml[(size_t)h * 2048 + row], m1 = Ml[(size_t)(16 + h) * 2048 + row];
    float l0 = Ll[(size_t)h * 2048 + row], l1 = Ll[(size_t)(16 + h) * 2048 + row];
    float mm = fmaxf(m0, m1);
    float a0 = __expf(m0 - mm), a1 = __expf(m1 - mm);
    float inv = 1.f / (l0 * a0 + l1 * a1);
    a0 *= inv; a1 *= inv;
    const float* p0 = Op + (size_t)row * 2048 + col0;
    const float* p1 = Op + (size_t)(2048 + row) * 2048 + col0;
    float4 x0 = *(const float4*)p0, x1 = *(const float4*)(p0 + 4);
    float4 y0 = *(const float4*)p1, y1 = *(const float4*)(p1 + 4);
    bfrag8 ov;
    ov[0] = f2bf(x0.x * a0 + y0.x * a1); ov[1] = f2bf(x0.y * a0 + y0.y * a1);
    ov[2] = f2bf(x0.z * a0 + y0.z * a1); ov[3] = f2bf(x0.w * a0 + y0.w * a1);
    ov[4] = f2bf(x1.x * a0 + y1.x * a1); ov[5] = f2bf(x1.y * a0 + y1.y * a1);
    ov[6] = f2bf(x1.z * a0 + y1.z * a1); ov[7] = f2bf(x1.w * a0 + y1.w * a1);
    *(bfrag8*)(Ob + (size_t)row * 2048 + col0) = ov;
}

// ---------------- elementwise ----------------
__global__ __launch_bounds__(256) void silu_mul_bf16_kernel(const float* __restrict__ g,
                                                            const float* __restrict__ u,
                                                            short* __restrict__ out) {
    size_t i = ((size_t)blockIdx.x * 256 + threadIdx.x) * 4;
    float4 x = *(const float4*)(g + i);
    float4 y = *(const float4*)(u + i);
    bfrag4 o;
    o[0] = f2bf(x.x / (1.f + __expf(-x.x)) * y.x);
    o[1] = f2bf(x.y / (1.f + __expf(-x.y)) * y.y);
    o[2] = f2bf(x.z / (1.f + __expf(-x.z)) * y.z);
    o[3] = f2bf(x.w / (1.f + __expf(-x.w)) * y.w);
    *(bfrag4*)(out + i) = o;
}

// ---------------- orchestration ----------------
extern "C" void kernel_launch(void* const* d_in, const int* in_sizes, int n_in,
                              void* d_out, int out_size, void* d_ws, size_t ws_size,
                              hipStream_t stream) {
    const int*   ids   = (const int*)d_in[0];
    const float* emb   = (const float*)d_in[1];
    const float* Wq    = (const float*)d_in[2];
    const float* Wk    = (const float*)d_in[3];
    const float* Wv    = (const float*)d_in[4];
    const float* Wo    = (const float*)d_in[5];
    const float* Wg    = (const float*)d_in[6];
    const float* Wu    = (const float*)d_in[7];
    const float* Wd    = (const float*)d_in[8];
    const float* ln1   = (const float*)d_in[9];
    const float* ln2   = (const float*)d_in[10];
    const float* fnorm = (const float*)d_in[11];
    const float* lmh   = (const float*)d_in[12];
    const float* kc    = (const float*)d_in[13];
    const float* vc    = (const float*)d_in[14];
    float* logits = (float*)d_out;

    char* ws = (char*)d_ws;
    float* hbuf   = (float*)(ws + ((size_t)0 << 20));    // 16 MB f32 residual
    short* xb     = (short*)(ws + ((size_t)16 << 20));   // 8 MB bf16 normed x
    float* qkvbuf = (float*)(ws + ((size_t)24 << 20));   // 32 MB f32 [2048][4096]; also attn partials
    short* Ob     = (short*)(ws + ((size_t)56 << 20));   // 8 MB bf16 attn out
    short* wt     = (short*)(ws + ((size_t)64 << 20));   // 34 MB bf16 transposed weight scratch
    short* Qb     = (short*)(ws + ((size_t)98 << 20));   // 8 MB
    short* Kf     = (short*)(ws + ((size_t)106 << 20));  // 16 MB
    short* Vt     = (short*)(ws + ((size_t)122 << 20));  // 16 MB
    float* gbuf   = (float*)(ws + ((size_t)138 << 20));  // 64 MB
    float* ubuf   = (float*)(ws + ((size_t)202 << 20));  // 64 MB
    short* gb     = (short*)(ws + ((size_t)266 << 20));  // 32 MB
    float* mlb    = (float*)(ws + ((size_t)298 << 20));  // 0.5 MB: Ml (2*16*2048) + Ll
    float* Mlp    = mlb;
    float* Llp    = mlb + 2 * 16 * 2048;
    short* lmwt   = (short*)(ws + ((size_t)138 << 20));  // 131 MB, reuses gbuf/ubuf/gb region

    embed_kernel<<<2048, 256, 0, stream>>>(ids, emb, hbuf);

    for (int l = 0; l < 2; ++l) {
        const float* wq  = Wq + (size_t)l * 2048 * 2048;
        const float* wk  = Wk + (size_t)l * 2048 * 1024;
        const float* wv  = Wv + (size_t)l * 2048 * 1024;
        const float* wo  = Wo + (size_t)l * 2048 * 2048;
        const float* wg  = Wg + (size_t)l * 2048 * 8192;
        const float* wu  = Wu + (size_t)l * 2048 * 8192;
        const float* wd  = Wd + (size_t)l * 8192 * 2048;
        const float* l1  = ln1 + (size_t)l * 2048;
        const float* l2  = ln2 + (size_t)l * 2048;
        const float* kcl = kc + (size_t)l * 16 * 2048 * 128;
        const float* vcl = vc + (size_t)l * 16 * 2048 * 128;

        rmsnorm_bf16_kernel<<<2048, 256, 0, stream>>>(hbuf, l1, xb);
        wconv_kernel<<<dim3(32, 32), 256, 0, stream>>>(wq, wt, 2048, 2048);
        wconv_kernel<<<dim3(32, 16), 256, 0, stream>>>(wk, wt + (size_t)2048 * 2048, 2048, 1024);
        wconv_kernel<<<dim3(32, 16), 256, 0, stream>>>(wv, wt + (size_t)3072 * 2048, 2048, 1024);
        gemm_bt<128, false><<<dim3(16, 32), 256, 0, stream>>>(xb, wt, qkvbuf, 2048, 4096);
        prep_q_kernel<<<dim3(16, 2048), 128, 0, stream>>>(qkvbuf, Qb);
        prep_k_kernel<<<dim3(16, 4096), 128, 0, stream>>>(kcl, qkvbuf, Kf);
        prep_v_kernel<<<dim3(16, 64), 256, 0, stream>>>(vcl, qkvbuf, Vt);
        attn_kernel<<<dim3(16, 32, 2), 256, 0, stream>>>(Qb, Kf, Vt, qkvbuf, Mlp, Llp);
        attn_combine<<<2048, 256, 0, stream>>>(qkvbuf, Mlp, Llp, Ob);
        wconv_kernel<<<dim3(32, 32), 256, 0, stream>>>(wo, wt, 2048, 2048);
        gemm_bt<64, true><<<dim3(32, 16), 256, 0, stream>>>(Ob, wt, hbuf, 2048, 2048);
        rmsnorm_bf16_kernel<<<2048, 256, 0, stream>>>(hbuf, l2, xb);
        wconv_kernel<<<dim3(32, 128), 256, 0, stream>>>(wg, wt, 2048, 8192);
        gemm_bt<128, false><<<dim3(16, 64), 256, 0, stream>>>(xb, wt, gbuf, 2048, 8192);
        wconv_kernel<<<dim3(32, 128), 256, 0, stream>>>(wu, wt, 2048, 8192);
        gemm_bt<128, false><<<dim3(16, 64), 256, 0, stream>>>(xb, wt, ubuf, 2048, 8192);
        silu_mul_bf16_kernel<<<16384, 256, 0, stream>>>(gbuf, ubuf, gb);
        wconv_kernel<<<dim3(128, 32), 256, 0, stream>>>(wd, wt, 8192, 2048);
        gemm_bt<64, true><<<dim3(32, 16), 256, 0, stream>>>(gb, wt, hbuf, 8192, 2048);
    }
    rmsnorm_bf16_kernel<<<2048, 256, 0, stream>>>(hbuf, fnorm, xb);
    wconv_kernel<<<dim3(32, 500), 256, 0, stream>>>(lmh, lmwt, 2048, 32000);
    gemm_bt<128, false><<<dim3(16, 250), 256, 0, stream>>>(xb, lmwt, logits, 2048, 32000);
}

// Round 5
// 1742.809 us; speedup vs baseline: 2.0626x; 1.1677x over previous
//
#include <hip/hip_runtime.h>

typedef __attribute__((ext_vector_type(8))) short bfrag8;   // 8 x bf16 (4 VGPRs)
typedef __attribute__((ext_vector_type(4))) short bfrag4;   // 4 x bf16
typedef __attribute__((ext_vector_type(4))) float facc4;    // 4 x f32 accum

#define DEV_INLINE __device__ __forceinline__

DEV_INLINE short f2bf(float f) {
    union { float f; unsigned u; } x; x.f = f;
    unsigned r = (x.u + 0x7FFFu + ((x.u >> 16) & 1u)) >> 16;
    return (short)r;
}

DEV_INLINE unsigned pack_bf2(float a, float b) {
    return (unsigned)(unsigned short)f2bf(a) | ((unsigned)(unsigned short)f2bf(b) << 16);
}

// async global->LDS, 16B per lane; dest = wave-uniform base + lane*16
#define GL2LDS(gp, lp) __builtin_amdgcn_global_load_lds( \
    (const __attribute__((address_space(1))) void*)(gp), \
    (__attribute__((address_space(3))) void*)(lp), 16, 0, 0)

#define MFMA16(a, b, c) __builtin_amdgcn_mfma_f32_16x16x32_bf16((a), (b), (c), 0, 0, 0)

// ---------------- embedding gather ----------------
__global__ __launch_bounds__(256) void embed_kernel(const int* __restrict__ ids,
                                                    const float* __restrict__ emb,
                                                    float* __restrict__ h) {
    int s = blockIdx.x;
    int id = ids[s];
    const float* src = emb + (size_t)id * 2048;
    float* dst = h + (size_t)s * 2048;
    int t = threadIdx.x;
    float4 a = *(const float4*)(src + t * 8);
    float4 b = *(const float4*)(src + t * 8 + 4);
    *(float4*)(dst + t * 8) = a;
    *(float4*)(dst + t * 8 + 4) = b;
}

// ---------------- RMSNorm rows of 2048, bf16 out ----------------
__global__ __launch_bounds__(256) void rmsnorm_bf16_kernel(const float* __restrict__ in,
                                                           const float* __restrict__ w,
                                                           short* __restrict__ out) {
    int row = blockIdx.x;
    const float* x = in + (size_t)row * 2048;
    short* y = out + (size_t)row * 2048;
    int t = threadIdx.x;
    float4 a = *(const float4*)(x + t * 8);
    float4 b = *(const float4*)(x + t * 8 + 4);
    float ss = a.x*a.x + a.y*a.y + a.z*a.z + a.w*a.w
             + b.x*b.x + b.y*b.y + b.z*b.z + b.w*b.w;
#pragma unroll
    for (int off = 32; off >= 1; off >>= 1) ss += __shfl_xor(ss, off);
    __shared__ float red[4];
    if ((t & 63) == 0) red[t >> 6] = ss;
    __syncthreads();
    float tot = red[0] + red[1] + red[2] + red[3];
    float sc = rsqrtf(tot * (1.0f / 2048.0f) + 1e-6f);
    float4 wa = *(const float4*)(w + t * 8);
    float4 wb = *(const float4*)(w + t * 8 + 4);
    bfrag8 o;
    o[0] = f2bf(a.x * sc * wa.x); o[1] = f2bf(a.y * sc * wa.y);
    o[2] = f2bf(a.z * sc * wa.z); o[3] = f2bf(a.w * sc * wa.w);
    o[4] = f2bf(b.x * sc * wb.x); o[5] = f2bf(b.y * sc * wb.y);
    o[6] = f2bf(b.z * sc * wb.z); o[7] = f2bf(b.w * sc * wb.w);
    *(bfrag8*)(y + t * 8) = o;
}

// ---------------- weight transpose-convert: W[K][N] f32 -> Wt[N][K] bf16 ----------------
__global__ __launch_bounds__(256) void wconv_kernel(const float* __restrict__ W,
                                                    short* __restrict__ Wt,
                                                    int K, int N) {
    __shared__ short Lt[64][72];
    int k0 = blockIdx.x * 64, n0 = blockIdx.y * 64;
    int tid = threadIdx.x;
    int r = tid >> 4, c = (tid & 15) * 4;
#pragma unroll
    for (int j = 0; j < 4; ++j) {
        int k = r + j * 16;
        float4 v = *(const float4*)(W + (size_t)(k0 + k) * N + n0 + c);
        Lt[c + 0][k] = f2bf(v.x); Lt[c + 1][k] = f2bf(v.y);
        Lt[c + 2][k] = f2bf(v.z); Lt[c + 3][k] = f2bf(v.w);
    }
    __syncthreads();
    int n = tid >> 3, kk = (tid & 7) * 8;
#pragma unroll
    for (int j = 0; j < 2; ++j)
        *(bfrag8*)(Wt + (size_t)(n0 + n + j * 32) * K + k0 + kk) = *(const bfrag8*)&Lt[n + j * 32][kk];
}

// ---------------- GEMM (2-phase, small shapes): C = A * Bt^T ----------------
template<int BM, bool ADD>
__global__ __launch_bounds__(256) void gemm_bt(const short* __restrict__ A,
                                               const short* __restrict__ Bt,
                                               float* __restrict__ C,
                                               int K, int N) {
    __shared__ short As[BM * 32];
    __shared__ short Bs[128 * 32];
    constexpr int NW = (BM == 128) ? 4 : 2;
    int tid = threadIdx.x;
    int lane = tid & 63, wave = tid >> 6;

    int gx = gridDim.x;
    int nwg = gx * gridDim.y;
    int b = blockIdx.y * gx + blockIdx.x;
    int q = nwg >> 3, r8 = nwg & 7;
    int xcd = b & 7, idx = b >> 3;
    int lb = (xcd < r8) ? (xcd * (q + 1) + idx) : (r8 * (q + 1) + (xcd - r8) * q + idx);
    int bm = (lb % gx) * BM, bn = (lb / gx) * 128;

    int wr = (BM == 128) ? ((wave >> 1) * 64) : 0;
    int wc = (BM == 128) ? ((wave & 1) * 64) : (wave * 32);
    int lr = lane & 15, lg = lane >> 4;

    facc4 acc[4][NW];
#pragma unroll
    for (int m = 0; m < 4; ++m)
#pragma unroll
        for (int n = 0; n < NW; ++n) acc[m][n] = (facc4){0.f, 0.f, 0.f, 0.f};

    int stR = wave * 16 + (lane >> 2);
    int stK = (lane & 3) * 8;
    const short* Ag = A + (size_t)(bm + stR) * K + stK;
    const short* Bg = Bt + (size_t)(bn + stR) * K + stK;
    short* AsP = As + stR * 32 + stK;
    short* BsP = Bs + stR * 32 + stK;

    for (int k0 = 0; k0 < K; k0 += 32) {
        GL2LDS(Ag + k0, AsP);
        if (BM == 128) GL2LDS(Ag + (size_t)64 * K + k0, AsP + 64 * 32);
        GL2LDS(Bg + k0, BsP);
        GL2LDS(Bg + (size_t)64 * K + k0, BsP + 64 * 32);
        __syncthreads();
        bfrag8 a[4], bfr[NW];
#pragma unroll
        for (int m = 0; m < 4; ++m)
            a[m] = *(const bfrag8*)&As[(wr + m * 16 + lr) * 32 + lg * 8];
#pragma unroll
        for (int n = 0; n < NW; ++n)
            bfr[n] = *(const bfrag8*)&Bs[(wc + n * 16 + lr) * 32 + lg * 8];
#pragma unroll
        for (int m = 0; m < 4; ++m)
#pragma unroll
            for (int n = 0; n < NW; ++n)
                acc[m][n] = MFMA16(a[m], bfr[n], acc[m][n]);
        __syncthreads();
    }
#pragma unroll
    for (int m = 0; m < 4; ++m)
#pragma unroll
        for (int n = 0; n < NW; ++n)
#pragma unroll
            for (int r = 0; r < 4; ++r) {
                size_t ci = (size_t)(bm + wr + m * 16 + lg * 4 + r) * N + bn + wc + n * 16 + lr;
                C[ci] = ADD ? (C[ci] + acc[m][n][r]) : acc[m][n][r];
            }
}

// ---------------- GEMM (8-phase 256x256, big-N shapes) ----------------
// 512 thr / 8 waves (2Mx4N), BK=64, 128 KiB LDS as 4-half-slot ring per operand,
// chunk-XOR swizzle (T2), counted staging: tile t+1 issued at phase 0 of tile t,
// single vmcnt(0)+barrier per K-tile (T3/T4), setprio around MFMA (T5).
// Requires M%256==0, N%256==0, K%64==0, gridDim.x == M/256.
__global__ __launch_bounds__(512, 2) void gemm8(const short* __restrict__ A,
                                                const short* __restrict__ Bt,
                                                float* __restrict__ C,
                                                int K, int N) {
    __shared__ short lds[65536];   // 128 KiB: A halves [4][8192] | B halves at +32768
    char* ldsb = (char*)lds;
    int tid = threadIdx.x;
    int lane = tid & 63, wave = tid >> 6;
    int wm = wave >> 2, wn = wave & 3;
    int lr = lane & 15, lg = lane >> 4;

    int gx = gridDim.x;
    int nwg = gx * gridDim.y;
    int b = blockIdx.y * gx + blockIdx.x;
    int q8 = nwg >> 3, r8 = nwg & 7;
    int xcd = b & 7, idx = b >> 3;
    int lb = (xcd < r8) ? (xcd * (q8 + 1) + idx) : (r8 * (q8 + 1) + (xcd - r8) * q8 + idx);
    int bm = (lb % gx) * 256, bn = (lb / gx) * 256;

    facc4 acc[8][4];
#pragma unroll
    for (int m = 0; m < 8; ++m)
#pragma unroll
        for (int n = 0; n < 4; ++n) acc[m][n] = (facc4){0.f, 0.f, 0.f, 0.f};

    // staging geometry: thread covers LDS bytes [tid*16] and [8192 + tid*16] per half
    int rs = tid >> 3;                          // row within half (j=0); j=1 row = rs+64
    int swz = ((tid & 7) ^ (rs & 7)) * 8;       // pre-swizzled source k-chunk
    int d0 = tid * 16, d1 = 8192 + tid * 16;
    const size_t sK = (size_t)K;

    auto stage = [&](int u) {
        int sp = (u & 1) * 2;                   // half-slot pair for tile u
        int ko = u * 64 + swz;
        const short* Ab = A + (size_t)(bm + rs) * sK + ko;
        const short* Bb = Bt + (size_t)(bn + rs) * sK + ko;
        GL2LDS(Ab,            ldsb + sp * 16384 + d0);
        GL2LDS(Ab +  64 * sK, ldsb + sp * 16384 + d1);
        GL2LDS(Ab + 128 * sK, ldsb + (sp + 1) * 16384 + d0);
        GL2LDS(Ab + 192 * sK, ldsb + (sp + 1) * 16384 + d1);
        GL2LDS(Bb,            ldsb + 65536 + sp * 16384 + d0);
        GL2LDS(Bb +  64 * sK, ldsb + 65536 + sp * 16384 + d1);
        GL2LDS(Bb + 128 * sK, ldsb + 65536 + (sp + 1) * 16384 + d0);
        GL2LDS(Bb + 192 * sK, ldsb + 65536 + (sp + 1) * 16384 + d1);
    };

    int NT = K >> 6;
    stage(0);
    asm volatile("s_waitcnt vmcnt(0)" ::: "memory");
    __builtin_amdgcn_s_barrier();
    __builtin_amdgcn_sched_barrier(0);

    int ck0 = (lg ^ (lr & 7)) * 8;              // swizzled chunk (shorts) for kk=0; kk=1: ^32
    int aoff = lr * 64;
    int boff = ((wn & 1) * 64 + lr) * 64;

    for (int t = 0; t < NT; ++t) {
        int aA = ((t & 1) * 2 + wm) * 8192 + aoff;
        int bA = 32768 + ((t & 1) * 2 + (wn >> 1)) * 8192 + boff;
        bfrag8 af[4][2], bf[4][2];
        // ---- phase 0: read A m0-3 + B n0-1, issue next-tile staging, MFMA q(0,0)
#pragma unroll
        for (int i = 0; i < 4; ++i) {
            af[i][0] = *(const bfrag8*)&lds[aA + i * 1024 + ck0];
            af[i][1] = *(const bfrag8*)&lds[aA + i * 1024 + (ck0 ^ 32)];
        }
#pragma unroll
        for (int n = 0; n < 2; ++n) {
            bf[n][0] = *(const bfrag8*)&lds[bA + n * 1024 + ck0];
            bf[n][1] = *(const bfrag8*)&lds[bA + n * 1024 + (ck0 ^ 32)];
        }
        if (t + 1 < NT) stage(t + 1);
        __builtin_amdgcn_s_setprio(1);
#pragma unroll
        for (int i = 0; i < 4; ++i)
#pragma unroll
            for (int n = 0; n < 2; ++n) {
                acc[i][n] = MFMA16(af[i][0], bf[n][0], acc[i][n]);
                acc[i][n] = MFMA16(af[i][1], bf[n][1], acc[i][n]);
            }
        __builtin_amdgcn_s_setprio(0);
        __builtin_amdgcn_s_barrier();
        __builtin_amdgcn_sched_barrier(0);
        // ---- phase 1: read B n2-3, MFMA q(0,1)
#pragma unroll
        for (int n = 2; n < 4; ++n) {
            bf[n][0] = *(const bfrag8*)&lds[bA + n * 1024 + ck0];
            bf[n][1] = *(const bfrag8*)&lds[bA + n * 1024 + (ck0 ^ 32)];
        }
        __builtin_amdgcn_s_setprio(1);
#pragma unroll
        for (int i = 0; i < 4; ++i)
#pragma unroll
            for (int n = 2; n < 4; ++n) {
                acc[i][n] = MFMA16(af[i][0], bf[n][0], acc[i][n]);
                acc[i][n] = MFMA16(af[i][1], bf[n][1], acc[i][n]);
            }
        __builtin_amdgcn_s_setprio(0);
        __builtin_amdgcn_s_barrier();
        __builtin_amdgcn_sched_barrier(0);
        // ---- phase 2: read A m4-7, MFMA q(1,0)
#pragma unroll
        for (int i = 0; i < 4; ++i) {
            af[i][0] = *(const bfrag8*)&lds[aA + (4 + i) * 1024 + ck0];
            af[i][1] = *(const bfrag8*)&lds[aA + (4 + i) * 1024 + (ck0 ^ 32)];
        }
        __builtin_amdgcn_s_setprio(1);
#pragma unroll
        for (int i = 0; i < 4; ++i)
#pragma unroll
            for (int n = 0; n < 2; ++n) {
                acc[4 + i][n] = MFMA16(af[i][0], bf[n][0], acc[4 + i][n]);
                acc[4 + i][n] = MFMA16(af[i][1], bf[n][1], acc[4 + i][n]);
            }
        __builtin_amdgcn_s_setprio(0);
        __builtin_amdgcn_s_barrier();
        __builtin_amdgcn_sched_barrier(0);
        // ---- phase 3: MFMA q(1,1), then the ONLY vmcnt of this K-tile
        __builtin_amdgcn_s_setprio(1);
#pragma unroll
        for (int i = 0; i < 4; ++i)
#pragma unroll
            for (int n = 2; n < 4; ++n) {
                acc[4 + i][n] = MFMA16(af[i][0], bf[n][0], acc[4 + i][n]);
                acc[4 + i][n] = MFMA16(af[i][1], bf[n][1], acc[4 + i][n]);
            }
        __builtin_amdgcn_s_setprio(0);
        asm volatile("s_waitcnt vmcnt(0)" ::: "memory");
        __builtin_amdgcn_s_barrier();
        __builtin_amdgcn_sched_barrier(0);
    }

    int crow = bm + wm * 128 + lg * 4;
    int ccol = bn + wn * 64 + lr;
#pragma unroll
    for (int m = 0; m < 8; ++m)
#pragma unroll
        for (int n = 0; n < 4; ++n)
#pragma unroll
            for (int r = 0; r < 4; ++r)
                C[(size_t)(crow + m * 16 + r) * N + ccol + n * 16] = acc[m][n][r];
}

// ---------------- RoPE ----------------
#define ROPE_C 0.20762050593046010f   // log2(10000)/64
#define INV2PI 0.15915494309189535f
#define TWOPI  6.283185307179586f
#define QK_SCALE 0.08838834764831845f // 1/sqrt(128), folded into Q

DEV_INLINE void rope_sc(float pos, int j, float* s, float* c) {
    float f = pos * exp2f(-(float)j * ROPE_C);
    float r = f * INV2PI;
    r -= floorf(r);
    __sincosf(r * TWOPI, s, c);
}

__global__ __launch_bounds__(128) void prep_q_kernel(const float* __restrict__ qkv,
                                                     short* __restrict__ Qb) {
    int h = blockIdx.x, s = blockIdx.y, d = threadIdx.x;
    const float* src = qkv + (size_t)s * 4096 + h * 128;
    float x = src[d], xp = src[d ^ 64];
    float sn, c;
    rope_sc((float)(2048 + s), d & 63, &sn, &c);
    float o = (d < 64) ? (x * c - xp * sn) : (x * c + xp * sn);
    Qb[((size_t)h * 2048 + s) * 128 + d] = f2bf(o * QK_SCALE);
}

__global__ __launch_bounds__(128) void prep_k_kernel(const float* __restrict__ kc,
                                                     const float* __restrict__ qkv,
                                                     short* __restrict__ Kf) {
    int h = blockIdx.x, t = blockIdx.y, d = threadIdx.x;
    float x, xp;
    if (t < 2048) {
        const float* src = kc + ((size_t)h * 2048 + t) * 128;
        x = src[d]; xp = src[d ^ 64];
    } else {
        const float* src = qkv + (size_t)(t - 2048) * 4096 + 2048 + (h >> 1) * 128;
        x = src[d]; xp = src[d ^ 64];
    }
    float sn, c;
    rope_sc((float)t, d & 63, &sn, &c);
    float o = (d < 64) ? (x * c - xp * sn) : (x * c + xp * sn);
    Kf[((size_t)h * 4096 + t) * 128 + d] = f2bf(o);
}

__global__ __launch_bounds__(256) void prep_v_kernel(const float* __restrict__ vc,
                                                     const float* __restrict__ qkv,
                                                     short* __restrict__ Vt) {
    int h = blockIdx.x;
    int t0 = blockIdx.y * 64;
    __shared__ short Lt[128][72];
    int tid = threadIdx.x;
    int r = tid >> 2;
    int c0 = (tid & 3) * 32;
    int t = t0 + r;
    const float* src = (t < 2048)
        ? vc + ((size_t)h * 2048 + t) * 128 + c0
        : qkv + (size_t)(t - 2048) * 4096 + 3072 + (h >> 1) * 128 + c0;
#pragma unroll
    for (int i = 0; i < 32; i += 4) {
        float4 v = *(const float4*)(src + i);
        Lt[c0 + i + 0][r] = f2bf(v.x);
        Lt[c0 + i + 1][r] = f2bf(v.y);
        Lt[c0 + i + 2][r] = f2bf(v.z);
        Lt[c0 + i + 3][r] = f2bf(v.w);
    }
    __syncthreads();
    int d = tid >> 1;
    int hh = (tid & 1) * 32;
    short* dst = Vt + ((size_t)h * 128 + d) * 4096 + t0 + hh;
    const short* srcl = &Lt[d][hh];
#pragma unroll
    for (int i = 0; i < 32; i += 8)
        *(bfrag8*)(dst + i) = *(const bfrag8*)(srcl + i);
}

// ---------------- flash attention v3 (unchanged from R4) ----------------
__global__ __launch_bounds__(256, 4) void attn_kernel(const short* __restrict__ Q,
                                                      const short* __restrict__ Kf,
                                                      const short* __restrict__ Vt,
                                                      float* __restrict__ Op,
                                                      float* __restrict__ Ml,
                                                      float* __restrict__ Ll) {
    int h = blockIdx.x;
    int qb = blockIdx.y * 64;
    int z = blockIdx.z;
    int tid = threadIdx.x;
    int lane = tid & 63, wave = tid >> 6;
    int lr = lane & 15, lg = lane >> 4;
    int qrow = qb + wave * 16;
    int qg = 2048 + qrow + lr;

    __shared__ short Ks[2][4096];
    __shared__ short Vs[2][4096];
    __shared__ short P[4][16][40];

    const short* kbase = Kf + (size_t)h * 4096 * 128;
    const short* vbase = Vt + (size_t)h * 128 * 4096;

    bfrag8 aq[4];
    {
        const short* qp = Q + ((size_t)h * 2048 + qrow + lr) * 128 + lg * 8;
#pragma unroll
        for (int dt = 0; dt < 4; ++dt) aq[dt] = *(const bfrag8*)(qp + dt * 32);
    }
    facc4 o[8];
#pragma unroll
    for (int n = 0; n < 8; ++n) o[n] = (facc4){0.f, 0.f, 0.f, 0.f};
    float m = -1e30f, l = 0.f;

    auto stage = [&](int buf, int t0) {
#pragma unroll
        for (int half = 0; half < 2; ++half) {
            int rk = half * 16 + wave * 4 + (lane >> 4);
            int ck = (lane & 15) ^ (rk & 7);
            GL2LDS(kbase + (size_t)(t0 + rk) * 128 + ck * 8,
                   &Ks[buf][half * 2048 + wave * 512 + lane * 8]);
            int rv = half * 64 + wave * 16 + (lane >> 2);
            int cv = (lane & 3) ^ ((rv >> 1) & 3);
            GL2LDS(vbase + (size_t)rv * 4096 + t0 + cv * 8,
                   &Vs[buf][half * 2048 + wave * 512 + lane * 8]);
        }
    };

    auto process = [&](int buf, int t0) {
        facc4 s0 = (facc4){0.f, 0.f, 0.f, 0.f}, s1 = (facc4){0.f, 0.f, 0.f, 0.f};
        int r0 = lr, r1 = 16 + lr;
#pragma unroll
        for (int dt = 0; dt < 4; ++dt) {
            bfrag8 k0 = *(const bfrag8*)&Ks[buf][r0 * 128 + (((dt * 4 + lg) ^ (r0 & 7)) * 8)];
            bfrag8 k1 = *(const bfrag8*)&Ks[buf][r1 * 128 + (((dt * 4 + lg) ^ (r1 & 7)) * 8)];
            s0 = MFMA16(k0, aq[dt], s0);
            s1 = MFMA16(k1, aq[dt], s1);
        }
        float mx = m;
#pragma unroll
        for (int r = 0; r < 4; ++r) {
            int k0i = t0 + lg * 4 + r;
            if (k0i > qg)      s0[r] = -1e30f;
            if (k0i + 16 > qg) s1[r] = -1e30f;
            mx = fmaxf(mx, fmaxf(s0[r], s1[r]));
        }
        mx = fmaxf(mx, __shfl_xor(mx, 16));
        mx = fmaxf(mx, __shfl_xor(mx, 32));
        if (__any(mx > m + 8.f)) {
            float alpha = __expf(m - mx);
            m = mx;
            l *= alpha;
            float ab[4];
#pragma unroll
            for (int r = 0; r < 4; ++r) ab[r] = __shfl(alpha, lg * 4 + r);
#pragma unroll
            for (int n = 0; n < 8; ++n) {
                o[n][0] *= ab[0]; o[n][1] *= ab[1]; o[n][2] *= ab[2]; o[n][3] *= ab[3];
            }
        }
        float ps = 0.f;
#pragma unroll
        for (int r = 0; r < 4; ++r) {
            s0[r] = __expf(s0[r] - m); ps += s0[r];
            s1[r] = __expf(s1[r] - m); ps += s1[r];
        }
        ps += __shfl_xor(ps, 16);
        ps += __shfl_xor(ps, 32);
        l += ps;
        unsigned* prow = (unsigned*)&P[wave][lr][0];
        prow[lg * 2]     = pack_bf2(s0[0], s0[1]);
        prow[lg * 2 + 1] = pack_bf2(s0[2], s0[3]);
        prow[8 + lg * 2]     = pack_bf2(s1[0], s1[1]);
        prow[8 + lg * 2 + 1] = pack_bf2(s1[2], s1[3]);
        bfrag8 ap = *(const bfrag8*)&P[wave][lr][lg * 8];
#pragma unroll
        for (int n = 0; n < 8; ++n) {
            int rv = n * 16 + lr;
            bfrag8 vf = *(const bfrag8*)&Vs[buf][rv * 32 + ((lg ^ ((rv >> 1) & 3)) * 8)];
            o[n] = MFMA16(ap, vf, o[n]);
        }
    };

    int NT = ((2048 + qb + 63) >> 5) + 1;
    int i0 = z ? (NT >> 1) : 0;
    int i1 = z ? NT : (NT >> 1);

    stage(0, i0 * 32);
    __syncthreads();
    int buf = 0;
    for (int i = i0; i < i1; ++i) {
        if (i + 1 < i1) stage(buf ^ 1, (i + 1) * 32);
        process(buf, i * 32);
        __syncthreads();
        buf ^= 1;
    }

#pragma unroll
    for (int n = 0; n < 8; ++n)
#pragma unroll
        for (int r = 0; r < 4; ++r)
            Op[(size_t)(z * 2048 + qrow + lg * 4 + r) * 2048 + h * 128 + n * 16 + lr] = o[n][r];
    if (lg == 0) {
        Ml[((size_t)z * 16 + h) * 2048 + qrow + lr] = m;
        Ll[((size_t)z * 16 + h) * 2048 + qrow + lr] = l;
    }
}

__global__ __launch_bounds__(256) void attn_combine(const float* __restrict__ Op,
                                                    const float* __restrict__ Ml,
                                                    const float* __restrict__ Ll,
                                                    short* __restrict__ Ob) {
    int row = blockIdx.x, t = threadIdx.x;
    int col0 = t * 8;
    int h = col0 >> 7;
    float m0 = Ml[(size_t)h * 2048 + row], m1 = Ml[(size_t)(16 + h) * 2048 + row];
    float l0 = Ll[(size_t)h * 2048 + row], l1 = Ll[(size_t)(16 + h) * 2048 + row];
    float mm = fmaxf(m0, m1);
    float a0 = __expf(m0 - mm), a1 = __expf(m1 - mm);
    float inv = 1.f / (l0 * a0 + l1 * a1);
    a0 *= inv; a1 *= inv;
    const float* p0 = Op + (size_t)row * 2048 + col0;
    const float* p1 = Op + (size_t)(2048 + row) * 2048 + col0;
    float4 x0 = *(const float4*)p0, x1 = *(const float4*)(p0 + 4);
    float4 y0 = *(const float4*)p1, y1 = *(const float4*)(p1 + 4);
    bfrag8 ov;
    ov[0] = f2bf(x0.x * a0 + y0.x * a1); ov[1] = f2bf(x0.y * a0 + y0.y * a1);
    ov[2] = f2bf(x0.z * a0 + y0.z * a1); ov[3] = f2bf(x0.w * a0 + y0.w * a1);
    ov[4] = f2bf(x1.x * a0 + y1.x * a1); ov[5] = f2bf(x1.y * a0 + y1.y * a1);
    ov[6] = f2bf(x1.z * a0 + y1.z * a1); ov[7] = f2bf(x1.w * a0 + y1.w * a1);
    *(bfrag8*)(Ob + (size_t)row * 2048 + col0) = ov;
}

// ---------------- elementwise ----------------
__global__ __launch_bounds__(256) void silu_mul_bf16_kernel(const float* __restrict__ g,
                                                            const float* __restrict__ u,
                                                            short* __restrict__ out) {
    size_t i = ((size_t)blockIdx.x * 256 + threadIdx.x) * 4;
    float4 x = *(const float4*)(g + i);
    float4 y = *(const float4*)(u + i);
    bfrag4 o;
    o[0] = f2bf(x.x / (1.f + __expf(-x.x)) * y.x);
    o[1] = f2bf(x.y / (1.f + __expf(-x.y)) * y.y);
    o[2] = f2bf(x.z / (1.f + __expf(-x.z)) * y.z);
    o[3] = f2bf(x.w / (1.f + __expf(-x.w)) * y.w);
    *(bfrag4*)(out + i) = o;
}

// ---------------- orchestration ----------------
extern "C" void kernel_launch(void* const* d_in, const int* in_sizes, int n_in,
                              void* d_out, int out_size, void* d_ws, size_t ws_size,
                              hipStream_t stream) {
    const int*   ids   = (const int*)d_in[0];
    const float* emb   = (const float*)d_in[1];
    const float* Wq    = (const float*)d_in[2];
    const float* Wk    = (const float*)d_in[3];
    const float* Wv    = (const float*)d_in[4];
    const float* Wo    = (const float*)d_in[5];
    const float* Wg    = (const float*)d_in[6];
    const float* Wu    = (const float*)d_in[7];
    const float* Wd    = (const float*)d_in[8];
    const float* ln1   = (const float*)d_in[9];
    const float* ln2   = (const float*)d_in[10];
    const float* fnorm = (const float*)d_in[11];
    const float* lmh   = (const float*)d_in[12];
    const float* kc    = (const float*)d_in[13];
    const float* vc    = (const float*)d_in[14];
    float* logits = (float*)d_out;

    char* ws = (char*)d_ws;
    float* hbuf   = (float*)(ws + ((size_t)0 << 20));    // 16 MB f32 residual
    short* xb     = (short*)(ws + ((size_t)16 << 20));   // 8 MB bf16 normed x
    float* qkvbuf = (float*)(ws + ((size_t)24 << 20));   // 32 MB f32; also attn partials
    short* Ob     = (short*)(ws + ((size_t)56 << 20));   // 8 MB bf16 attn out
    short* wt     = (short*)(ws + ((size_t)64 << 20));   // 34 MB bf16 transposed weight scratch
    short* Qb     = (short*)(ws + ((size_t)98 << 20));   // 8 MB
    short* Kf     = (short*)(ws + ((size_t)106 << 20));  // 16 MB
    short* Vt     = (short*)(ws + ((size_t)122 << 20));  // 16 MB
    float* gbuf   = (float*)(ws + ((size_t)138 << 20));  // 64 MB
    float* ubuf   = (float*)(ws + ((size_t)202 << 20));  // 64 MB
    short* gb     = (short*)(ws + ((size_t)266 << 20));  // 32 MB
    float* mlb    = (float*)(ws + ((size_t)298 << 20));  // 0.5 MB Ml+Ll
    float* Mlp    = mlb;
    float* Llp    = mlb + 2 * 16 * 2048;
    short* lmwt   = (short*)(ws + ((size_t)138 << 20));  // 131 MB, reuses gbuf/ubuf/gb region

    embed_kernel<<<2048, 256, 0, stream>>>(ids, emb, hbuf);

    for (int l = 0; l < 2; ++l) {
        const float* wq  = Wq + (size_t)l * 2048 * 2048;
        const float* wk  = Wk + (size_t)l * 2048 * 1024;
        const float* wv  = Wv + (size_t)l * 2048 * 1024;
        const float* wo  = Wo + (size_t)l * 2048 * 2048;
        const float* wg  = Wg + (size_t)l * 2048 * 8192;
        const float* wu  = Wu + (size_t)l * 2048 * 8192;
        const float* wd  = Wd + (size_t)l * 8192 * 2048;
        const float* l1  = ln1 + (size_t)l * 2048;
        const float* l2  = ln2 + (size_t)l * 2048;
        const float* kcl = kc + (size_t)l * 16 * 2048 * 128;
        const float* vcl = vc + (size_t)l * 16 * 2048 * 128;

        rmsnorm_bf16_kernel<<<2048, 256, 0, stream>>>(hbuf, l1, xb);
        wconv_kernel<<<dim3(32, 32), 256, 0, stream>>>(wq, wt, 2048, 2048);
        wconv_kernel<<<dim3(32, 16), 256, 0, stream>>>(wk, wt + (size_t)2048 * 2048, 2048, 1024);
        wconv_kernel<<<dim3(32, 16), 256, 0, stream>>>(wv, wt + (size_t)3072 * 2048, 2048, 1024);
        gemm_bt<128, false><<<dim3(16, 32), 256, 0, stream>>>(xb, wt, qkvbuf, 2048, 4096);
        prep_q_kernel<<<dim3(16, 2048), 128, 0, stream>>>(qkvbuf, Qb);
        prep_k_kernel<<<dim3(16, 4096), 128, 0, stream>>>(kcl, qkvbuf, Kf);
        prep_v_kernel<<<dim3(16, 64), 256, 0, stream>>>(vcl, qkvbuf, Vt);
        attn_kernel<<<dim3(16, 32, 2), 256, 0, stream>>>(Qb, Kf, Vt, qkvbuf, Mlp, Llp);
        attn_combine<<<2048, 256, 0, stream>>>(qkvbuf, Mlp, Llp, Ob);
        wconv_kernel<<<dim3(32, 32), 256, 0, stream>>>(wo, wt, 2048, 2048);
        gemm_bt<64, true><<<dim3(32, 16), 256, 0, stream>>>(Ob, wt, hbuf, 2048, 2048);
        rmsnorm_bf16_kernel<<<2048, 256, 0, stream>>>(hbuf, l2, xb);
        wconv_kernel<<<dim3(32, 128), 256, 0, stream>>>(wg, wt, 2048, 8192);
        gemm8<<<dim3(8, 32), 512, 0, stream>>>(xb, wt, gbuf, 2048, 8192);
        wconv_kernel<<<dim3(32, 128), 256, 0, stream>>>(wu, wt, 2048, 8192);
        gemm8<<<dim3(8, 32), 512, 0, stream>>>(xb, wt, ubuf, 2048, 8192);
        silu_mul_bf16_kernel<<<16384, 256, 0, stream>>>(gbuf, ubuf, gb);
        wconv_kernel<<<dim3(128, 32), 256, 0, stream>>>(wd, wt, 8192, 2048);
        gemm_bt<64, true><<<dim3(32, 16), 256, 0, stream>>>(gb, wt, hbuf, 8192, 2048);
    }
    rmsnorm_bf16_kernel<<<2048, 256, 0, stream>>>(hbuf, fnorm, xb);
    wconv_kernel<<<dim3(32, 500), 256, 0, stream>>>(lmh, lmwt, 2048, 32000);
    gemm8<<<dim3(8, 125), 512, 0, stream>>>(xb, lmwt, logits, 2048, 32000);
}